// Round 13
// baseline (95.640 us; speedup 1.0000x reference)
//
#include <hip/hip_runtime.h>
#include <hip/hip_fp16.h>
#include <math.h>

#define NBATCH 16384
#define EPSV 1e-5f
#define IMGW 4   // images per wave (pipelined)

typedef short short8 __attribute__((ext_vector_type(8)));
typedef _Float16 half8_t __attribute__((ext_vector_type(8)));
typedef short short2v __attribute__((ext_vector_type(2)));
typedef float f32x4 __attribute__((ext_vector_type(4)));
union V8 { uint4 u; short8 s; };
union VH { uint4 u; half8_t h; };

__device__ __forceinline__ unsigned short f2bf(float f) {
    unsigned int x = __float_as_uint(f);
    return (unsigned short)((x + 0x7fffu + ((x >> 16) & 1u)) >> 16);  // RNE
}
__device__ __forceinline__ unsigned short f2h(float f) {
    return __half_as_ushort(__float2half(f));   // v_cvt_f16_f32, RNE
}
__device__ __forceinline__ __half2 u2h(unsigned int u) { return __builtin_bit_cast(__half2, u); }
__device__ __forceinline__ unsigned int h2u(__half2 h) { return __builtin_bit_cast(unsigned int, h); }

// ---------------------------------------------------------------------------
// K0: prep all weight transforms once.
//   wt f16 [64][800] with PERMUTED K: k<784 -> k = pos*16 + oc  (oc<16, pos<49)
//   maps to fc1w[n][oc*49 + pos]; k in {784,785,786} identity; k>=787 zero.
// ---------------------------------------------------------------------------
__global__ __launch_bounds__(256) void k_prep(
    const float* __restrict__ fc1w, const float* __restrict__ w2,
    const float* __restrict__ w1, const float* __restrict__ b1,
    unsigned short* __restrict__ wt, unsigned short* __restrict__ af16,
    unsigned int* __restrict__ w1h2, unsigned int* __restrict__ b1h2)
{
    int i = blockIdx.x * 256 + threadIdx.x;
    if (i < 51200) {
        int n = i / 800, k = i - n * 800;
        float v;
        if (k < 784) {
            int pos = k >> 4, oc = k & 15;
            v = fc1w[n * 787 + oc * 49 + pos];
        } else if (k < 787) {
            v = fc1w[n * 787 + k];
        } else {
            v = 0.f;
        }
        wt[i] = f2h(v);
    } else if (i < 52736) {
        int a = i - 51200;
        int slot = a >> 7, rem = a & 127, oc = rem >> 3, ic = rem & 7;
        float v = (slot < 9) ? w2[oc * 72 + ic * 9 + slot] : 0.f;
        af16[a] = f2h(v);
    } else if (i < 52808) {
        int k = i - 52736;
        unsigned int hb = f2h(w1[k]);
        w1h2[k] = hb | (hb << 16);
    } else if (i < 52816) {
        int k = i - 52808;
        unsigned int hb = f2h(b1[k]);
        b1h2[k] = hb | (hb << 16);
    }
}

// ---------------------------------------------------------------------------
// K1: one wave = one block; IMGW images pipelined: img i+1's x-loads are
//     issued BEFORE img i's compute, so global latency hides under compute.
//     Single sxu buffer (wave DS ops are in-order). Rolled r11 phase code +
//     r12 permuted-K b64 epilogue stores.
// ---------------------------------------------------------------------------
#define SXS 15   // sxu row stride in u32

__global__ __launch_bounds__(64, 4) void k_conv(
    const float* __restrict__ x,
    const float* __restrict__ s1w, const float* __restrict__ s1b,
    const float* __restrict__ s2w, const float* __restrict__ s2b,
    const float* __restrict__ fw, const float* __restrict__ fb,
    const float* __restrict__ b2,
    const unsigned short* __restrict__ Afg,   // [12][16][8] f16
    const unsigned int* __restrict__ w1h2g,   // [72]
    const unsigned int* __restrict__ b1h2g,   // [8]
    unsigned short* __restrict__ comb)
{
    const int l = threadIdx.x;

    __shared__ unsigned int sxu[30 * SXS];                 // f16 col-pairs
    __shared__ __align__(16) unsigned short sf1[16 * 136]; // conv1 pooled, channels-last f16

    // ---- one-time init (rows 0/29 of sxu; sf1 pad ring) ---------------------
    for (int i = l; i < 30 * SXS; i += 64) sxu[i] = 0u;
    if (l < 60) {
        int R, C;
        if (l < 16)      { R = 0;      C = l; }
        else if (l < 32) { R = 15;     C = l - 16; }
        else if (l < 46) { R = l - 31; C = 0; }
        else             { R = l - 45; C = 15; }
        *reinterpret_cast<uint4*>(&sf1[R * 136 + C * 8]) = uint4{0u, 0u, 0u, 0u};
    }

    // filter + sampler weights: uniform -> scalar loads, hoisted out of loop
    const __half2 fwh0 = __float2half2_rn(fw[0]);
    const __half2 fwh1 = __float2half2_rn(fw[1]);
    const __half2 fwh2 = __float2half2_rn(fw[2]);
    const __half2 fwh3 = __float2half2_rn(fw[3]);
    const __half2 fbh  = __float2half2_rn(fb[0]);
    float s1wv[8], s1bv[4], s2wv[8];
    #pragma unroll
    for (int k = 0; k < 8; ++k) s1wv[k] = s1w[k];
    #pragma unroll
    for (int k = 0; k < 4; ++k) s1bv[k] = s1b[k];
    #pragma unroll
    for (int k = 0; k < 8; ++k) s2wv[k] = s2w[k];
    const float s2b0 = s2b[0], s2b1 = s2b[1];

    // conv2 MFMA lane constants
    const int n = l & 15, g = l >> 4;
    const int qr = n & 7;
    const int q = (qr < 7) ? qr : 6;       // clamp dead lane
    const int dr = n >> 3;
    VH af[3];
    const unsigned short* ps[3];
    #pragma unroll
    for (int s = 0; s < 3; ++s) {
        const int slot = s * 4 + g;
        const int u = slot / 3, v = slot - 3 * (slot / 3);
        const int offs = (slot <= 8) ? (u * 136 + v * 8) : 0;
        ps[s] = sf1 + dr * 136 + 16 * q + offs;   // pp adds 272 u16
        af[s].u = *reinterpret_cast<const uint4*>(Afg + ((slot * 16 + n) << 3));
    }
    float biasv[4];
    #pragma unroll
    for (int i = 0; i < 4; ++i) biasv[i] = b2[4 * g + i];

    // stage-phase lane constants
    int srow[7], sww[7];
    #pragma unroll
    for (int k = 0; k < 7; ++k) {
        int u0 = l + k * 64;
        srow[k] = u0 / 15;
        sww[k]  = u0 - srow[k] * 15;
    }

    const int b0 = blockIdx.x * IMGW;

    // ---- prologue: issue img 0's loads --------------------------------------
    float xlo[7], xhi[7];
    {
        const float* xb = x + (size_t)b0 * 784;
        #pragma unroll
        for (int k = 0; k < 7; ++k) {
            const int u0 = l + k * 64;
            if (u0 < 420) {
                const float* base = xb + srow[k] * 28;
                xlo[k] = (sww[k] == 0)  ? 0.f : base[2 * sww[k] - 1];
                xhi[k] = (sww[k] == 14) ? 0.f : base[2 * sww[k]];
            }
        }
    }

    // ---- pipelined image loop ----------------------------------------------
    #pragma unroll
    for (int img = 0; img < IMGW; ++img) {
        const int b = b0 + img;
        unsigned short* crow = comb + (size_t)b * 800;

        // write current image's x into LDS (vmcnt wait happens here)
        #pragma unroll
        for (int k = 0; k < 7; ++k) {
            const int u0 = l + k * 64;
            if (u0 < 420)
                sxu[(srow[k] + 1) * SXS + sww[k]] = h2u(__floats2half2_rn(xlo[k], xhi[k]));
        }

        // issue NEXT image's loads now; they fly under this image's compute
        float ylo[7], yhi[7];
        if (img + 1 < IMGW) {
            const float* xb = x + (size_t)(b + 1) * 784;
            #pragma unroll
            for (int k = 0; k < 7; ++k) {
                const int u0 = l + k * 64;
                if (u0 < 420) {
                    const float* base = xb + srow[k] * 28;
                    ylo[k] = (sww[k] == 0)  ? 0.f : base[2 * sww[k] - 1];
                    yhi[k] = (sww[k] == 14) ? 0.f : base[2 * sww[k]];
                }
            }
        }

        // zero K-tail of this row (independent store)
        if (l < 13) crow[787 + l] = 0;

        // ---- filter conv + sigmoid wave-sum --------------------------------
        float fsum = 0.f;
        for (int u0 = l; u0 < 378; u0 += 64) {
            int r = u0 / 14, cp = u0 - (u0 / 14) * 14;
            unsigned int A1 = sxu[(r + 1) * SXS + cp], B1 = sxu[(r + 1) * SXS + cp + 1];
            unsigned int A2 = sxu[(r + 2) * SXS + cp], B2 = sxu[(r + 2) * SXS + cp + 1];
            __half2 al1 = u2h(__builtin_amdgcn_alignbit(B1, A1, 16));
            __half2 al2 = u2h(__builtin_amdgcn_alignbit(B2, A2, 16));
            __half2 acc = __hfma2(fwh0, al1,
                          __hfma2(fwh1, u2h(B1),
                          __hfma2(fwh2, al2,
                          __hfma2(fwh3, u2h(B2), fbh))));
            float2 f = __half22float2(acc);
            fsum += __frcp_rn(1.f + __expf(-f.x));
            if (cp < 13) fsum += __frcp_rn(1.f + __expf(-f.y));
        }
        #pragma unroll
        for (int off = 32; off > 0; off >>= 1)
            fsum += __shfl_xor(fsum, off, 64);

        // ---- conv1: pooled cell (p,j), 8 oc, packed f16 --------------------
        for (int i = l; i < 196; i += 64) {
            const int p = i / 14, j = i - (i / 14) * 14;
            unsigned int A[4], B[4], M[4];
            #pragma unroll
            for (int u = 0; u < 4; ++u) {
                A[u] = sxu[(2 * p + u) * SXS + j];
                B[u] = sxu[(2 * p + u) * SXS + j + 1];
                M[u] = __builtin_amdgcn_alignbit(B[u], A[u], 16);
            }
            unsigned short outv[8];
            #pragma unroll
            for (int oc = 0; oc < 8; ++oc) {
                __half2 a0 = u2h(b1h2g[oc]), a1 = a0;
                #pragma unroll
                for (int u = 0; u < 3; ++u) {
                    #pragma unroll
                    for (int v = 0; v < 3; ++v) {
                        const __half2 wv = u2h(w1h2g[oc * 9 + u * 3 + v]);
                        const unsigned int p0 = (v == 0) ? A[u]     : ((v == 1) ? M[u]     : B[u]);
                        const unsigned int p1 = (v == 0) ? A[u + 1] : ((v == 1) ? M[u + 1] : B[u + 1]);
                        a0 = __hfma2(wv, u2h(p0), a0);
                        a1 = __hfma2(wv, u2h(p1), a1);
                    }
                }
                short2v s0 = __builtin_bit_cast(short2v, a0);
                short2v s1 = __builtin_bit_cast(short2v, a1);
                short2v mm = __builtin_elementwise_max(s0, s1);
                short m = mm[0] > mm[1] ? mm[0] : mm[1];
                if (m < 0) m = 0;
                outv[oc] = (unsigned short)m;
            }
            *reinterpret_cast<uint4*>(&sf1[(p + 1) * 136 + (j + 1) * 8]) =
                *reinterpret_cast<const uint4*>(outv);
        }

        // ---- conv2 via f16 MFMA; permuted-K b64 stores ---------------------
        float f0r = 0.f, f1r = 0.f;
        #pragma unroll
        for (int pp = 0; pp < 7; ++pp) {
            f32x4 acc0 = {0.f, 0.f, 0.f, 0.f}, acc1 = {0.f, 0.f, 0.f, 0.f};
            #pragma unroll
            for (int s = 0; s < 3; ++s) {
                VH c0, c1;
                c0.u = *reinterpret_cast<const uint4*>(ps[s] + pp * 272);
                c1.u = *reinterpret_cast<const uint4*>(ps[s] + pp * 272 + 8);
                acc0 = __builtin_amdgcn_mfma_f32_16x16x32_f16(af[s].h, c0.h, acc0, 0, 0, 0);
                acc1 = __builtin_amdgcn_mfma_f32_16x16x32_f16(af[s].h, c1.h, acc1, 0, 0, 0);
            }
            float vv[4];
            #pragma unroll
            for (int i = 0; i < 4; ++i) {
                float m = fmaxf(acc0[i], acc1[i]);
                m = fmaxf(m, __shfl_xor(m, 8, 64));
                vv[i] = fmaxf(m + biasv[i], 0.f);
            }
            if (pp == 0) {
                f0r = __shfl(vv[0], 0, 64);
                f1r = __shfl(vv[0], 1, 64);
            }
            if (n < 7) {
                uint2 pk;
                pk.x = (unsigned int)f2h(vv[0]) | ((unsigned int)f2h(vv[1]) << 16);
                pk.y = (unsigned int)f2h(vv[2]) | ((unsigned int)f2h(vv[3]) << 16);
                *reinterpret_cast<uint2*>(&crow[(pp * 7 + q) * 16 + g * 4]) = pk;
            }
        }

        // ---- sampler + filter-mean (lane 0) --------------------------------
        if (l == 0) {
            crow[786] = f2h(fsum * (1.f / 729.f));
            float h[4];
            #pragma unroll
            for (int k = 0; k < 4; ++k) {
                float y = fmaf(f0r, s1wv[2 * k], fmaf(f1r, s1wv[2 * k + 1], s1bv[k]));
                float e = __expf(2.f * y);
                h[k] = (e - 1.f) * __frcp_rn(e + 1.f);
            }
            float l0 = s2b0, l1 = s2b1;
            #pragma unroll
            for (int k = 0; k < 4; ++k) {
                l0 = fmaf(h[k], s2wv[k], l0);
                l1 = fmaf(h[k], s2wv[4 + k], l1);
            }
            float mx = fmaxf(l0, l1);
            float e0 = __expf(l0 - mx), e1 = __expf(l1 - mx);
            float inv = __frcp_rn(e0 + e1);
            crow[784] = f2h(e0 * inv);
            crow[785] = f2h(e1 * inv);
        }

        // rotate prefetch registers
        if (img + 1 < IMGW) {
            #pragma unroll
            for (int k = 0; k < 7; ++k) { xlo[k] = ylo[k]; xhi[k] = yhi[k]; }
        }
    }
}

// ---------------------------------------------------------------------------
// K2: f16 MFMA GEMM  h1 = relu(comb[16384,800] @ wt[64,800]^T + fc1b)
//     (K-dimension of comb/wt is permuted identically -> result unchanged)
// ---------------------------------------------------------------------------
__global__ __launch_bounds__(256) void k_fc(
    const unsigned short* __restrict__ A,
    const unsigned short* __restrict__ Bw,
    const float* __restrict__ fc1b,
    const float* __restrict__ fc2w, const float* __restrict__ fc2b,
    float* __restrict__ out, float* __restrict__ part)
{
    __shared__ uint4 Asm[2][256];
    __shared__ uint4 Bsm[2][256];
    __shared__ float sh[64][68];
    __shared__ float sfc2[4][64];
    __shared__ float pacc[4][8];

    const int t = threadIdx.x;
    const int w = t >> 6, l = t & 63;
    const int blk = blockIdx.x;

    sfc2[t >> 6][t & 63] = fc2w[t];

    const int srow = t >> 2, skbp = t & 3;
    const int skbl = skbp ^ ((srow >> 1) & 3);
    const uint4* Ag = reinterpret_cast<const uint4*>(A) + ((size_t)blk * 64 + srow) * 100;
    const uint4* Bg = reinterpret_cast<const uint4*>(Bw) + (size_t)srow * 100;
    const int sidx = srow * 4 + skbp;

    const int arow = w * 16 + (l & 15);
    const int aidx = arow * 4 + ((l >> 4) ^ ((arow >> 1) & 3));
    int bidx[4];
    #pragma unroll
    for (int nf = 0; nf < 4; ++nf) {
        int nn = nf * 16 + (l & 15);
        bidx[nf] = nn * 4 + ((l >> 4) ^ ((nn >> 1) & 3));
    }

    f32x4 acc0 = {0.f, 0.f, 0.f, 0.f}, acc1 = acc0, acc2 = acc0, acc3 = acc0;

    Asm[0][sidx] = Ag[skbl];
    Bsm[0][sidx] = Bg[skbl];

    int buf = 0;
    for (int s = 0; s < 25; ++s) {
        __syncthreads();
        if (s < 24) {
            Asm[buf ^ 1][sidx] = Ag[(s + 1) * 4 + skbl];
            Bsm[buf ^ 1][sidx] = Bg[(s + 1) * 4 + skbl];
        }
        VH av; av.u = Asm[buf][aidx];
        VH b0; b0.u = Bsm[buf][bidx[0]];
        VH b1; b1.u = Bsm[buf][bidx[1]];
        VH b2; b2.u = Bsm[buf][bidx[2]];
        VH b3; b3.u = Bsm[buf][bidx[3]];
        acc0 = __builtin_amdgcn_mfma_f32_16x16x32_f16(av.h, b0.h, acc0, 0, 0, 0);
        acc1 = __builtin_amdgcn_mfma_f32_16x16x32_f16(av.h, b1.h, acc1, 0, 0, 0);
        acc2 = __builtin_amdgcn_mfma_f32_16x16x32_f16(av.h, b2.h, acc2, 0, 0, 0);
        acc3 = __builtin_amdgcn_mfma_f32_16x16x32_f16(av.h, b3.h, acc3, 0, 0, 0);
        buf ^= 1;
    }

    {
        const int c0 = l & 15, r0 = w * 16 + (l >> 4) * 4;
        float fb0 = fc1b[c0], fb1 = fc1b[16 + c0], fb2 = fc1b[32 + c0], fb3 = fc1b[48 + c0];
        #pragma unroll
        for (int r = 0; r < 4; ++r) {
            sh[r0 + r][c0]      = fmaxf(acc0[r] + fb0, 0.f);
            sh[r0 + r][16 + c0] = fmaxf(acc1[r] + fb1, 0.f);
            sh[r0 + r][32 + c0] = fmaxf(acc2[r] + fb2, 0.f);
            sh[r0 + r][48 + c0] = fmaxf(acc3[r] + fb3, 0.f);
        }
    }
    __syncthreads();

    {
        const int row = t >> 2, oo = t & 3;
        float s = fc2b[oo];
        #pragma unroll 8
        for (int o = 0; o < 64; ++o)
            s = fmaf(sh[row][o], sfc2[oo][o], s);
        out[((size_t)blk * 64 + row) * 4 + oo] = s;

        float rs = s, rq = s * s;
        #pragma unroll
        for (int off = 4; off < 64; off <<= 1) {
            rs += __shfl_xor(rs, off, 64);
            rq += __shfl_xor(rq, off, 64);
        }
        if (l < 4) pacc[w][l] = rs;
        else if (l < 8) pacc[w][l] = rq;
    }
    __syncthreads();
    if (t < 8)
        part[blk * 8 + t] = pacc[0][t] + pacc[1][t] + pacc[2][t] + pacc[3][t];
}

// ---------------------------------------------------------------------------
// BN finalize + apply
// ---------------------------------------------------------------------------
__global__ void k_bnfinal(const float* __restrict__ part,
                          const float* __restrict__ g, const float* __restrict__ bb,
                          float* __restrict__ ss, int nblocks)
{
    const int t = threadIdx.x;  // 64
    float s[8];
    #pragma unroll
    for (int i = 0; i < 8; ++i) s[i] = 0.f;
    for (int idx = t; idx < nblocks; idx += 64)
        #pragma unroll
        for (int i = 0; i < 8; ++i) s[i] += part[idx * 8 + i];
    #pragma unroll
    for (int i = 0; i < 8; ++i)
        #pragma unroll
        for (int off = 32; off > 0; off >>= 1)
            s[i] += __shfl_xor(s[i], off, 64);
    if (t == 0) {
        const float invB = 1.f / 16384.f;
        #pragma unroll
        for (int j = 0; j < 4; ++j) {
            float mu = s[j] * invB;
            float var = s[4 + j] * invB - mu * mu;
            float sc = g[j] * rsqrtf(var + EPSV);
            ss[j] = sc;
            ss[4 + j] = bb[j] - mu * sc;
        }
    }
}

__global__ __launch_bounds__(256) void k_bnapply(const float* __restrict__ ss,
                                                 float* __restrict__ out)
{
    const int row = blockIdx.x * 256 + threadIdx.x;
    float4 v = reinterpret_cast<float4*>(out)[row];
    v.x = fmaf(v.x, ss[0], ss[4]);
    v.y = fmaf(v.y, ss[1], ss[5]);
    v.z = fmaf(v.z, ss[2], ss[6]);
    v.w = fmaf(v.w, ss[3], ss[7]);
    reinterpret_cast<float4*>(out)[row] = v;
}

// ===========================================================================
// Fallback path (round-2 kernels) — used if ws_size is too small
// ===========================================================================
__global__ __launch_bounds__(256) void k_transpose_fb(const float* __restrict__ in,
                                                      float* __restrict__ out)
{
    int i = blockIdx.x * 256 + threadIdx.x;
    if (i < 787 * 64) {
        int k = i >> 6, o = i & 63;
        out[i] = in[o * 787 + k];
    }
}

#define SF1F(ic, r, c) sf1[(ic) * 324 + (r) * 20 + (c)]

__global__ __launch_bounds__(256) void k_fused_fb(
    const float* __restrict__ x,
    const float* __restrict__ w1, const float* __restrict__ b1,
    const float* __restrict__ w2, const float* __restrict__ b2,
    const float* __restrict__ s1w, const float* __restrict__ s1b,
    const float* __restrict__ s2w, const float* __restrict__ s2b,
    const float* __restrict__ fw, const float* __restrict__ fb,
    const float* __restrict__ wt, const float* __restrict__ fc1b,
    const float* __restrict__ fc2w, const float* __restrict__ fc2b,
    float* __restrict__ pre)
{
    const int b = blockIdx.x;
    const int t = threadIdx.x;

    __shared__ float sxA[30][20];
    __shared__ float sxB[30][20];
    __shared__ float sf1[8 * 324];
    __shared__ float scomb[788];
    __shared__ float sw1[72];
    __shared__ float sb1[8];
    __shared__ float sw2p[16 * 76];
    __shared__ float sb2[16];
    __shared__ float sh1p[4][64];
    __shared__ float sh1[64];
    __shared__ float sred[4];
    __shared__ float ssm[27];

    for (int i = t; i < 600; i += 256) { (&sxA[0][0])[i] = 0.f; (&sxB[0][0])[i] = 0.f; }
    for (int i = t; i < 8 * 324; i += 256) sf1[i] = 0.f;
    if (t < 72) sw1[t] = w1[t];
    if (t < 8) sb1[t] = b1[t];
    for (int i = t; i < 1152; i += 256) {
        int oc = i / 72, rem = i - oc * 72;
        sw2p[oc * 76 + rem] = w2[i];
    }
    if (t < 16) sb2[t] = b2[t];
    if (t < 8) ssm[t] = s1w[t];
    else if (t < 12) ssm[t] = s1b[t - 8];
    else if (t < 20) ssm[t] = s2w[t - 12];
    else if (t < 22) ssm[t] = s2b[t - 20];
    else if (t < 26) ssm[t] = fw[t - 22];
    else if (t == 26) ssm[t] = fb[0];
    __syncthreads();

    const float* xb = x + (size_t)b * 784;
    for (int i = t; i < 784; i += 256) {
        int r = i / 28, c = i - (i / 28) * 28;
        float v = xb[i];
        int pr = r + 1, pc = c + 1;
        if (pc <= 15) sxA[pr][pc] = v;
        if (pc >= 14) sxB[pr][pc - 14] = v;
    }
    __syncthreads();

    {
        const float fw00 = ssm[22], fw01 = ssm[23], fw10 = ssm[24], fw11 = ssm[25];
        const float fbv = ssm[26];
        float fsum = 0.f;
        for (int i = t; i < 729; i += 256) {
            int r = i / 27, c = i - (i / 27) * 27;
            float x00, x01, x10, x11;
            if (c <= 13) {
                x00 = sxA[r + 1][c + 1]; x01 = sxA[r + 1][c + 2];
                x10 = sxA[r + 2][c + 1]; x11 = sxA[r + 2][c + 2];
            } else {
                int cb = c - 14;
                x00 = sxB[r + 1][cb + 1]; x01 = sxB[r + 1][cb + 2];
                x10 = sxB[r + 2][cb + 1]; x11 = sxB[r + 2][cb + 2];
            }
            float v = fbv;
            v = fmaf(x00, fw00, v); v = fmaf(x01, fw01, v);
            v = fmaf(x10, fw10, v); v = fmaf(x11, fw11, v);
            fsum += 1.f / (1.f + expf(-v));
        }
        #pragma unroll
        for (int off = 32; off > 0; off >>= 1)
            fsum += __shfl_xor(fsum, off, 64);
        if ((t & 63) == 0) sred[t >> 6] = fsum;
    }

    {
        const int half = t >> 7;
        const int id = t & 127;
        if (id < 112) {
            const int p = id >> 3, oc = id & 7;
            const float* base = half ? &sxB[0][0] : &sxA[0][0];
            float X[4][16];
            #pragma unroll
            for (int u = 0; u < 4; ++u) {
                const float4* rp = reinterpret_cast<const float4*>(base + (2 * p + u) * 20);
                float4 a = rp[0], bb4 = rp[1], c4 = rp[2], d4 = rp[3];
                X[u][0] = a.x;  X[u][1] = a.y;  X[u][2] = a.z;  X[u][3] = a.w;
                X[u][4] = bb4.x; X[u][5] = bb4.y; X[u][6] = bb4.z; X[u][7] = bb4.w;
                X[u][8] = c4.x;  X[u][9] = c4.y;  X[u][10] = c4.z; X[u][11] = c4.w;
                X[u][12] = d4.x; X[u][13] = d4.y; X[u][14] = d4.z; X[u][15] = d4.w;
            }
            float W[9];
            #pragma unroll
            for (int k = 0; k < 9; ++k) W[k] = sw1[oc * 9 + k];
            const float bias = sb1[oc];
            const int j0 = half * 7;
            #pragma unroll
            for (int jj = 0; jj < 7; ++jj) {
                float m = 0.f;
                #pragma unroll
                for (int dr = 0; dr < 2; ++dr)
                    #pragma unroll
                    for (int dc = 0; dc < 2; ++dc) {
                        float acc = bias;
                        #pragma unroll
                        for (int u = 0; u < 3; ++u)
                            #pragma unroll
                            for (int v = 0; v < 3; ++v)
                                acc = fmaf(X[dr + u][2 * jj + dc + v], W[u * 3 + v], acc);
                        m = fmaxf(m, acc);
                    }
                SF1F(oc, p + 1, j0 + jj + 1) = m;
            }
        }
    }
    __syncthreads();

    if (t < 112) {
        const int p = t >> 4, oc = t & 15;
        const float bias = sb2[oc];
        float acc[7][4];
        #pragma unroll
        for (int jj = 0; jj < 7; ++jj)
            #pragma unroll
            for (int s = 0; s < 4; ++s) acc[jj][s] = bias;
        for (int ic = 0; ic < 8; ++ic) {
            float X[4][16];
            #pragma unroll
            for (int u = 0; u < 4; ++u) {
                const float4* rp = reinterpret_cast<const float4*>(&SF1F(ic, 2 * p + u, 0));
                float4 a = rp[0], bb4 = rp[1], c4 = rp[2], d4 = rp[3];
                X[u][0] = a.x;  X[u][1] = a.y;  X[u][2] = a.z;  X[u][3] = a.w;
                X[u][4] = bb4.x; X[u][5] = bb4.y; X[u][6] = bb4.z; X[u][7] = bb4.w;
                X[u][8] = c4.x;  X[u][9] = c4.y;  X[u][10] = c4.z; X[u][11] = c4.w;
                X[u][12] = d4.x; X[u][13] = d4.y; X[u][14] = d4.z; X[u][15] = d4.w;
            }
            float W[9];
            #pragma unroll
            for (int k = 0; k < 9; ++k) W[k] = sw2p[oc * 76 + ic * 9 + k];
            #pragma unroll
            for (int jj = 0; jj < 7; ++jj)
                #pragma unroll
                for (int dr = 0; dr < 2; ++dr)
                    #pragma unroll
                    for (int dc = 0; dc < 2; ++dc)
                        #pragma unroll
                        for (int u = 0; u < 3; ++u)
                            #pragma unroll
                            for (int v = 0; v < 3; ++v)
                                acc[jj][dr * 2 + dc] =
                                    fmaf(X[dr + u][2 * jj + dc + v], W[u * 3 + v], acc[jj][dr * 2 + dc]);
        }
        #pragma unroll
        for (int jj = 0; jj < 7; ++jj) {
            float m = fmaxf(fmaxf(acc[jj][0], acc[jj][1]), fmaxf(acc[jj][2], acc[jj][3]));
            scomb[oc * 49 + p * 7 + jj] = fmaxf(m, 0.f);
        }
    }
    __syncthreads();

    if (t == 0) {
        scomb[786] = (sred[0] + sred[1] + sred[2] + sred[3]) * (1.f / 729.f);
        float f0 = scomb[0], f1 = scomb[1];
        float h[4];
        #pragma unroll
        for (int k = 0; k < 4; ++k)
            h[k] = tanhf(fmaf(f0, ssm[k * 2], fmaf(f1, ssm[k * 2 + 1], ssm[8 + k])));
        float l0 = ssm[20], l1 = ssm[21];
        #pragma unroll
        for (int k = 0; k < 4; ++k) {
            l0 = fmaf(h[k], ssm[12 + k], l0);
            l1 = fmaf(h[k], ssm[16 + k], l1);
        }
        float mx = fmaxf(l0, l1);
        float e0 = expf(l0 - mx), e1 = expf(l1 - mx);
        float inv = 1.f / (e0 + e1);
        scomb[784] = e0 * inv;
        scomb[785] = e1 * inv;
    }
    __syncthreads();

    {
        const int o = t & 63, w = t >> 6;
        const int k0 = w * 197;
        const int k1 = (w == 3) ? 787 : k0 + 197;
        const float* wp = wt + (size_t)k0 * 64 + o;
        float acc = 0.f;
        #pragma unroll 4
        for (int k = k0; k < k1; ++k) {
            acc = fmaf(scomb[k], *wp, acc);
            wp += 64;
        }
        sh1p[w][o] = acc;
    }
    __syncthreads();
    if (t < 64)
        sh1[t] = fmaxf(sh1p[0][t] + sh1p[1][t] + sh1p[2][t] + sh1p[3][t] + fc1b[t], 0.f);
    __syncthreads();

    {
        const int oo = t >> 6, lane = t & 63;
        float v = sh1[lane] * fc2w[oo * 64 + lane];
        #pragma unroll
        for (int off = 32; off > 0; off >>= 1)
            v += __shfl_xor(v, off, 64);
        if (lane == 0) pre[(size_t)b * 4 + oo] = v + fc2b[oo];
    }
}

__global__ __launch_bounds__(256) void k_bnstat_fb(const float* __restrict__ pre,
                                                   float* __restrict__ part)
{
    const int t = threadIdx.x;
    const int row = blockIdx.x * 256 + t;
    float4 v = reinterpret_cast<const float4*>(pre)[row];
    float s0 = v.x, s1 = v.y, s2 = v.z, s3 = v.w;
    float q0 = v.x * v.x, q1 = v.y * v.y, q2 = v.z * v.z, q3 = v.w * v.w;
    #pragma unroll
    for (int off = 32; off > 0; off >>= 1) {
        s0 += __shfl_xor(s0, off, 64);
        s1 += __shfl_xor(s1, off, 64);
        s2 += __shfl_xor(s2, off, 64);
        s3 += __shfl_xor(s3, off, 64);
        q0 += __shfl_xor(q0, off, 64);
        q1 += __shfl_xor(q1, off, 64);
        q2 += __shfl_xor(q2, off, 64);
        q3 += __shfl_xor(q3, off, 64);
    }
    __shared__ float acc[4][8];
    if ((t & 63) == 0) {
        int w = t >> 6;
        acc[w][0] = s0; acc[w][1] = s1; acc[w][2] = s2; acc[w][3] = s3;
        acc[w][4] = q0; acc[w][5] = q1; acc[w][6] = q2; acc[w][7] = q3;
    }
    __syncthreads();
    if (t < 8)
        part[blockIdx.x * 8 + t] = acc[0][t] + acc[1][t] + acc[2][t] + acc[3][t];
}

// ===========================================================================
extern "C" void kernel_launch(void* const* d_in, const int* in_sizes, int n_in,
                              void* d_out, int out_size, void* d_ws, size_t ws_size,
                              hipStream_t stream)
{
    const float* x    = (const float*)d_in[0];
    const float* w1   = (const float*)d_in[1];
    const float* b1   = (const float*)d_in[2];
    const float* w2   = (const float*)d_in[3];
    const float* b2   = (const float*)d_in[4];
    const float* s1w  = (const float*)d_in[5];
    const float* s1b  = (const float*)d_in[6];
    const float* s2w  = (const float*)d_in[7];
    const float* s2b  = (const float*)d_in[8];
    const float* fw   = (const float*)d_in[9];
    const float* fb   = (const float*)d_in[10];
    const float* fc1w = (const float*)d_in[11];
    const float* fc1b = (const float*)d_in[12];
    const float* fc2w = (const float*)d_in[13];
    const float* fc2b = (const float*)d_in[14];
    const float* bng  = (const float*)d_in[15];
    const float* bnb  = (const float*)d_in[16];

    float* out = (float*)d_out;

    const size_t COMB_BYTES = (size_t)NBATCH * 800 * 2;      // 26,214,400
    const size_t WT_BYTES   = 64 * 800 * 2;                  // 102,400
    const size_t AF16_BYTES = 1536 * 2;                      // 3,072
    const size_t W1H2_BYTES = 72 * 4;                        // 288
    const size_t B1H2_BYTES = 8 * 4;                         // 32
    const size_t PART_BYTES = 256 * 8 * 4;                   // 8,192
    const size_t NEED = COMB_BYTES + WT_BYTES + AF16_BYTES + W1H2_BYTES +
                        B1H2_BYTES + PART_BYTES + 32;

    if (ws_size >= NEED) {
        char* p = (char*)d_ws;
        unsigned short* comb = (unsigned short*)p;                     p += COMB_BYTES;
        unsigned short* wtbf = (unsigned short*)p;                     p += WT_BYTES;
        unsigned short* af16 = (unsigned short*)p;                     p += AF16_BYTES;
        unsigned int*   w1h2 = (unsigned int*)p;                       p += W1H2_BYTES;
        unsigned int*   b1h2 = (unsigned int*)p;                       p += B1H2_BYTES;
        float*          part = (float*)p;                              p += PART_BYTES;
        float*          ss   = (float*)p;

        k_prep<<<207, 256, 0, stream>>>(fc1w, w2, w1, b1, wtbf, af16, w1h2, b1h2);
        k_conv<<<NBATCH / IMGW, 64, 0, stream>>>(x, s1w, s1b, s2w, s2b, fw, fb, b2,
                                                 af16, w1h2, b1h2, comb);
        k_fc<<<256, 256, 0, stream>>>(comb, wtbf, fc1b, fc2w, fc2b, out, part);
        k_bnfinal<<<1, 64, 0, stream>>>(part, bng, bnb, ss, 256);
        k_bnapply<<<64, 256, 0, stream>>>(ss, out);
    } else {
        float* part = (float*)d_ws;
        float* ss   = part + 512;
        float* wt   = ss + 8;

        k_transpose_fb<<<197, 256, 0, stream>>>(fc1w, wt);
        k_fused_fb<<<NBATCH, 256, 0, stream>>>(x, w1, b1, w2, b2, s1w, s1b, s2w, s2b,
                                               fw, fb, wt, fc1b, fc2w, fc2b, out);
        k_bnstat_fb<<<64, 256, 0, stream>>>(out, part);
        k_bnfinal<<<1, 64, 0, stream>>>(part, bng, bnb, ss, 64);
        k_bnapply<<<64, 256, 0, stream>>>(ss, out);
    }
}

// Round 14
// 87.107 us; speedup vs baseline: 1.0980x; 1.0980x over previous
//
#include <hip/hip_runtime.h>
#include <hip/hip_fp16.h>
#include <math.h>

#define NBATCH 16384
#define EPSV 1e-5f

typedef short short8 __attribute__((ext_vector_type(8)));
typedef _Float16 half8_t __attribute__((ext_vector_type(8)));
typedef short short2v __attribute__((ext_vector_type(2)));
typedef float f32x4 __attribute__((ext_vector_type(4)));
union V8 { uint4 u; short8 s; };
union VH { uint4 u; half8_t h; };

__device__ __forceinline__ unsigned short f2bf(float f) {
    unsigned int x = __float_as_uint(f);
    return (unsigned short)((x + 0x7fffu + ((x >> 16) & 1u)) >> 16);  // RNE
}
__device__ __forceinline__ unsigned short f2h(float f) {
    return __half_as_ushort(__float2half(f));   // v_cvt_f16_f32, RNE
}
__device__ __forceinline__ __half2 u2h(unsigned int u) { return __builtin_bit_cast(__half2, u); }
__device__ __forceinline__ unsigned int h2u(__half2 h) { return __builtin_bit_cast(unsigned int, h); }

// ---------------------------------------------------------------------------
// K0: prep all weight transforms once.
//   wt f16 [64][800] with PERMUTED K: k<784 -> k = pos*16 + oc  (oc<16, pos<49)
//   maps to fc1w[n][oc*49 + pos]; k in {784,785,786} identity; k>=787 zero.
// ---------------------------------------------------------------------------
__global__ __launch_bounds__(256) void k_prep(
    const float* __restrict__ fc1w, const float* __restrict__ w2,
    const float* __restrict__ w1, const float* __restrict__ b1,
    unsigned short* __restrict__ wt, unsigned short* __restrict__ af16,
    unsigned int* __restrict__ w1h2, unsigned int* __restrict__ b1h2)
{
    int i = blockIdx.x * 256 + threadIdx.x;
    if (i < 51200) {
        int n = i / 800, k = i - n * 800;
        float v;
        if (k < 784) {
            int pos = k >> 4, oc = k & 15;
            v = fc1w[n * 787 + oc * 49 + pos];
        } else if (k < 787) {
            v = fc1w[n * 787 + k];
        } else {
            v = 0.f;
        }
        wt[i] = f2h(v);
    } else if (i < 52736) {
        int a = i - 51200;
        int slot = a >> 7, rem = a & 127, oc = rem >> 3, ic = rem & 7;
        float v = (slot < 9) ? w2[oc * 72 + ic * 9 + slot] : 0.f;
        af16[a] = f2h(v);
    } else if (i < 52808) {
        int k = i - 52736;
        unsigned int hb = f2h(w1[k]);
        w1h2[k] = hb | (hb << 16);
    } else if (i < 52816) {
        int k = i - 52808;
        unsigned int hb = f2h(b1[k]);
        b1h2[k] = hb | (hb << 16);
    }
}

// ---------------------------------------------------------------------------
// K1: one wave = one block = one image (round-11 structure, best measured);
//     rolled phase loops; r12 permuted-K b64 epilogue stores; no barriers.
// ---------------------------------------------------------------------------
#define SXS 15   // sxu row stride in u32

__global__ __launch_bounds__(64, 8) void k_conv(
    const float* __restrict__ x,
    const float* __restrict__ s1w, const float* __restrict__ s1b,
    const float* __restrict__ s2w, const float* __restrict__ s2b,
    const float* __restrict__ fw, const float* __restrict__ fb,
    const float* __restrict__ b2,
    const unsigned short* __restrict__ Afg,   // [12][16][8] f16
    const unsigned int* __restrict__ w1h2g,   // [72]
    const unsigned int* __restrict__ b1h2g,   // [8]
    unsigned short* __restrict__ comb)
{
    const int l = threadIdx.x;

    __shared__ unsigned int sxu[30 * SXS];                 // f16 col-pairs
    __shared__ __align__(16) unsigned short sf1[16 * 136]; // conv1 pooled, channels-last f16

    // ---- init (wave-private; no barriers anywhere) --------------------------
    for (int i = l; i < 30 * SXS; i += 64) sxu[i] = 0u;
    if (l < 60) {   // sf1 pad ring
        int R, C;
        if (l < 16)      { R = 0;      C = l; }
        else if (l < 32) { R = 15;     C = l - 16; }
        else if (l < 46) { R = l - 31; C = 0; }
        else             { R = l - 45; C = 15; }
        *reinterpret_cast<uint4*>(&sf1[R * 136 + C * 8]) = uint4{0u, 0u, 0u, 0u};
    }

    // filter weights: uniform addresses -> scalar loads
    const __half2 fwh0 = __float2half2_rn(fw[0]);
    const __half2 fwh1 = __float2half2_rn(fw[1]);
    const __half2 fwh2 = __float2half2_rn(fw[2]);
    const __half2 fwh3 = __float2half2_rn(fw[3]);
    const __half2 fbh  = __float2half2_rn(fb[0]);

    // conv2 MFMA lane constants
    const int n = l & 15, g = l >> 4;
    const int qr = n & 7;
    const int q = (qr < 7) ? qr : 6;       // clamp dead lane
    const int dr = n >> 3;
    VH af[3];
    const unsigned short* ps[3];
    #pragma unroll
    for (int s = 0; s < 3; ++s) {
        const int slot = s * 4 + g;
        const int u = slot / 3, v = slot - 3 * (slot / 3);
        const int offs = (slot <= 8) ? (u * 136 + v * 8) : 0;
        ps[s] = sf1 + dr * 136 + 16 * q + offs;   // pp adds 272 u16
        af[s].u = *reinterpret_cast<const uint4*>(Afg + ((slot * 16 + n) << 3));
    }
    float biasv[4];
    #pragma unroll
    for (int i = 0; i < 4; ++i) biasv[i] = b2[4 * g + i];

    // stage-phase lane constants
    int srow[7], sww[7];
    #pragma unroll
    for (int k = 0; k < 7; ++k) {
        int u0 = l + k * 64;
        srow[k] = u0 / 15;
        sww[k]  = u0 - srow[k] * 15;
    }

    // ---- this block's image ------------------------------------------------
    const int b = blockIdx.x;
    const float* xb = x + (size_t)b * 784;
    unsigned short* crow = comb + (size_t)b * 800;

    // zero the K-tail early (wt is 0 there, but comb holds poisoned bytes)
    if (l < 13) crow[787 + l] = 0;

    // stage x: batch ALL global loads first (misses overlap), then cvt+write
    float xlo[7], xhi[7];
    #pragma unroll
    for (int k = 0; k < 7; ++k) {
        const int u0 = l + k * 64;
        if (u0 < 420) {
            const float* base = xb + srow[k] * 28;
            xlo[k] = (sww[k] == 0)  ? 0.f : base[2 * sww[k] - 1];
            xhi[k] = (sww[k] == 14) ? 0.f : base[2 * sww[k]];
        }
    }
    #pragma unroll
    for (int k = 0; k < 7; ++k) {
        const int u0 = l + k * 64;
        if (u0 < 420)
            sxu[(srow[k] + 1) * SXS + sww[k]] = h2u(__floats2half2_rn(xlo[k], xhi[k]));
    }

    // ---- filter conv (2 positions per unit, packed f16) + sigmoid wave-sum --
    float fsum = 0.f;
    for (int u0 = l; u0 < 378; u0 += 64) {
        int r = u0 / 14, cp = u0 - (u0 / 14) * 14;
        unsigned int A1 = sxu[(r + 1) * SXS + cp], B1 = sxu[(r + 1) * SXS + cp + 1];
        unsigned int A2 = sxu[(r + 2) * SXS + cp], B2 = sxu[(r + 2) * SXS + cp + 1];
        __half2 al1 = u2h(__builtin_amdgcn_alignbit(B1, A1, 16));
        __half2 al2 = u2h(__builtin_amdgcn_alignbit(B2, A2, 16));
        __half2 acc = __hfma2(fwh0, al1,
                      __hfma2(fwh1, u2h(B1),
                      __hfma2(fwh2, al2,
                      __hfma2(fwh3, u2h(B2), fbh))));
        float2 f = __half22float2(acc);
        fsum += __frcp_rn(1.f + __expf(-f.x));
        if (cp < 13) fsum += __frcp_rn(1.f + __expf(-f.y));
    }
    #pragma unroll
    for (int off = 32; off > 0; off >>= 1)
        fsum += __shfl_xor(fsum, off, 64);

    // ---- conv1: pooled cell (p,j), 8 oc, packed f16 --------------------------
    for (int i = l; i < 196; i += 64) {
        const int p = i / 14, j = i - (i / 14) * 14;
        unsigned int A[4], B[4], M[4];
        #pragma unroll
        for (int u = 0; u < 4; ++u) {
            A[u] = sxu[(2 * p + u) * SXS + j];
            B[u] = sxu[(2 * p + u) * SXS + j + 1];
            M[u] = __builtin_amdgcn_alignbit(B[u], A[u], 16);
        }
        unsigned short outv[8];
        #pragma unroll
        for (int oc = 0; oc < 8; ++oc) {
            __half2 a0 = u2h(b1h2g[oc]), a1 = a0;
            #pragma unroll
            for (int u = 0; u < 3; ++u) {
                #pragma unroll
                for (int v = 0; v < 3; ++v) {
                    const __half2 wv = u2h(w1h2g[oc * 9 + u * 3 + v]);
                    const unsigned int p0 = (v == 0) ? A[u]     : ((v == 1) ? M[u]     : B[u]);
                    const unsigned int p1 = (v == 0) ? A[u + 1] : ((v == 1) ? M[u + 1] : B[u + 1]);
                    a0 = __hfma2(wv, u2h(p0), a0);
                    a1 = __hfma2(wv, u2h(p1), a1);
                }
            }
            short2v s0 = __builtin_bit_cast(short2v, a0);
            short2v s1 = __builtin_bit_cast(short2v, a1);
            short2v mm = __builtin_elementwise_max(s0, s1);
            short m = mm[0] > mm[1] ? mm[0] : mm[1];
            if (m < 0) m = 0;
            outv[oc] = (unsigned short)m;
        }
        *reinterpret_cast<uint4*>(&sf1[(p + 1) * 136 + (j + 1) * 8]) =
            *reinterpret_cast<const uint4*>(outv);
    }

    // ---- conv2 via f16 MFMA; permuted-K b64 stores ---------------------------
    float f0r = 0.f, f1r = 0.f;
    for (int pp = 0; pp < 7; ++pp) {
        f32x4 acc0 = {0.f, 0.f, 0.f, 0.f}, acc1 = {0.f, 0.f, 0.f, 0.f};
        #pragma unroll
        for (int s = 0; s < 3; ++s) {
            VH c0, c1;
            c0.u = *reinterpret_cast<const uint4*>(ps[s] + pp * 272);
            c1.u = *reinterpret_cast<const uint4*>(ps[s] + pp * 272 + 8);
            acc0 = __builtin_amdgcn_mfma_f32_16x16x32_f16(af[s].h, c0.h, acc0, 0, 0, 0);
            acc1 = __builtin_amdgcn_mfma_f32_16x16x32_f16(af[s].h, c1.h, acc1, 0, 0, 0);
        }
        float vv[4];
        #pragma unroll
        for (int i = 0; i < 4; ++i) {
            float m = fmaxf(acc0[i], acc1[i]);            // max over dc
            m = fmaxf(m, __shfl_xor(m, 8, 64));           // max over dr
            vv[i] = fmaxf(m + biasv[i], 0.f);
        }
        if (pp == 0) {
            f0r = __shfl(vv[0], 0, 64);                   // flat[0] (oc0,pos0)
            f1r = __shfl(vv[0], 1, 64);                   // flat[1] (oc0,pos1)
        }
        if (n < 7) {
            uint2 pk;
            pk.x = (unsigned int)f2h(vv[0]) | ((unsigned int)f2h(vv[1]) << 16);
            pk.y = (unsigned int)f2h(vv[2]) | ((unsigned int)f2h(vv[3]) << 16);
            *reinterpret_cast<uint2*>(&crow[(pp * 7 + q) * 16 + g * 4]) = pk;
        }
    }

    // ---- sampler + filter-mean (lane 0) --------------------------------------
    if (l == 0) {
        crow[786] = f2h(fsum * (1.f / 729.f));
        float h[4];
        #pragma unroll
        for (int k = 0; k < 4; ++k) {
            float y = fmaf(f0r, s1w[2 * k], fmaf(f1r, s1w[2 * k + 1], s1b[k]));
            float e = __expf(2.f * y);
            h[k] = (e - 1.f) * __frcp_rn(e + 1.f);
        }
        float l0 = s2b[0], l1 = s2b[1];
        #pragma unroll
        for (int k = 0; k < 4; ++k) {
            l0 = fmaf(h[k], s2w[k], l0);
            l1 = fmaf(h[k], s2w[4 + k], l1);
        }
        float mx = fmaxf(l0, l1);
        float e0 = __expf(l0 - mx), e1 = __expf(l1 - mx);
        float inv = __frcp_rn(e0 + e1);
        crow[784] = f2h(e0 * inv);
        crow[785] = f2h(e1 * inv);
    }
}

// ---------------------------------------------------------------------------
// K2: f16 MFMA GEMM  h1 = relu(comb[16384,800] @ wt[64,800]^T + fc1b)
//     epilogue: out = h1 @ fc2w^T + fc2b  (+ per-block BN partial stats)
// ---------------------------------------------------------------------------
__global__ __launch_bounds__(256) void k_fc(
    const unsigned short* __restrict__ A,
    const unsigned short* __restrict__ Bw,
    const float* __restrict__ fc1b,
    const float* __restrict__ fc2w, const float* __restrict__ fc2b,
    float* __restrict__ out, float* __restrict__ part)
{
    __shared__ uint4 Asm[2][256];
    __shared__ uint4 Bsm[2][256];
    __shared__ float sh[64][68];
    __shared__ float sfc2[4][64];
    __shared__ float pacc[4][8];

    const int t = threadIdx.x;
    const int w = t >> 6, l = t & 63;
    const int blk = blockIdx.x;

    sfc2[t >> 6][t & 63] = fc2w[t];

    const int srow = t >> 2, skbp = t & 3;
    const int skbl = skbp ^ ((srow >> 1) & 3);
    const uint4* Ag = reinterpret_cast<const uint4*>(A) + ((size_t)blk * 64 + srow) * 100;
    const uint4* Bg = reinterpret_cast<const uint4*>(Bw) + (size_t)srow * 100;
    const int sidx = srow * 4 + skbp;

    const int arow = w * 16 + (l & 15);
    const int aidx = arow * 4 + ((l >> 4) ^ ((arow >> 1) & 3));
    int bidx[4];
    #pragma unroll
    for (int nf = 0; nf < 4; ++nf) {
        int nn = nf * 16 + (l & 15);
        bidx[nf] = nn * 4 + ((l >> 4) ^ ((nn >> 1) & 3));
    }

    f32x4 acc0 = {0.f, 0.f, 0.f, 0.f}, acc1 = acc0, acc2 = acc0, acc3 = acc0;

    Asm[0][sidx] = Ag[skbl];
    Bsm[0][sidx] = Bg[skbl];

    int buf = 0;
    for (int s = 0; s < 25; ++s) {
        __syncthreads();
        if (s < 24) {
            Asm[buf ^ 1][sidx] = Ag[(s + 1) * 4 + skbl];
            Bsm[buf ^ 1][sidx] = Bg[(s + 1) * 4 + skbl];
        }
        VH av; av.u = Asm[buf][aidx];
        VH b0; b0.u = Bsm[buf][bidx[0]];
        VH b1; b1.u = Bsm[buf][bidx[1]];
        VH b2; b2.u = Bsm[buf][bidx[2]];
        VH b3; b3.u = Bsm[buf][bidx[3]];
        acc0 = __builtin_amdgcn_mfma_f32_16x16x32_f16(av.h, b0.h, acc0, 0, 0, 0);
        acc1 = __builtin_amdgcn_mfma_f32_16x16x32_f16(av.h, b1.h, acc1, 0, 0, 0);
        acc2 = __builtin_amdgcn_mfma_f32_16x16x32_f16(av.h, b2.h, acc2, 0, 0, 0);
        acc3 = __builtin_amdgcn_mfma_f32_16x16x32_f16(av.h, b3.h, acc3, 0, 0, 0);
        buf ^= 1;
    }

    {
        const int c0 = l & 15, r0 = w * 16 + (l >> 4) * 4;
        float fb0 = fc1b[c0], fb1 = fc1b[16 + c0], fb2 = fc1b[32 + c0], fb3 = fc1b[48 + c0];
        #pragma unroll
        for (int r = 0; r < 4; ++r) {
            sh[r0 + r][c0]      = fmaxf(acc0[r] + fb0, 0.f);
            sh[r0 + r][16 + c0] = fmaxf(acc1[r] + fb1, 0.f);
            sh[r0 + r][32 + c0] = fmaxf(acc2[r] + fb2, 0.f);
            sh[r0 + r][48 + c0] = fmaxf(acc3[r] + fb3, 0.f);
        }
    }
    __syncthreads();

    {
        const int row = t >> 2, oo = t & 3;
        float s = fc2b[oo];
        #pragma unroll 8
        for (int o = 0; o < 64; ++o)
            s = fmaf(sh[row][o], sfc2[oo][o], s);
        out[((size_t)blk * 64 + row) * 4 + oo] = s;

        float rs = s, rq = s * s;
        #pragma unroll
        for (int off = 4; off < 64; off <<= 1) {
            rs += __shfl_xor(rs, off, 64);
            rq += __shfl_xor(rq, off, 64);
        }
        if (l < 4) pacc[w][l] = rs;
        else if (l < 8) pacc[w][l] = rq;
    }
    __syncthreads();
    if (t < 8)
        part[blk * 8 + t] = pacc[0][t] + pacc[1][t] + pacc[2][t] + pacc[3][t];
}

// ---------------------------------------------------------------------------
// K3: merged BN finalize + apply. 64 blocks x 256 threads; each block reduces
//     part[256][8] itself (2048 floats, deterministic) and normalizes its
//     256-row chunk of out in place. Deletes the separate k_bnfinal launch.
// ---------------------------------------------------------------------------
__global__ __launch_bounds__(256) void k_bnapply(const float* __restrict__ part,
                                                 const float* __restrict__ g,
                                                 const float* __restrict__ bb,
                                                 float* __restrict__ out)
{
    const int t = threadIdx.x;
    __shared__ float red[4][8];

    float s[8];
    #pragma unroll
    for (int i = 0; i < 8; ++i) s[i] = part[t * 8 + i];
    #pragma unroll
    for (int i = 0; i < 8; ++i)
        #pragma unroll
        for (int off = 32; off > 0; off >>= 1)
            s[i] += __shfl_xor(s[i], off, 64);
    if ((t & 63) == 0) {
        #pragma unroll
        for (int i = 0; i < 8; ++i) red[t >> 6][i] = s[i];
    }
    __syncthreads();

    float sc[4], sh[4];
    {
        const float invB = 1.f / 16384.f;
        #pragma unroll
        for (int j = 0; j < 4; ++j) {
            float tot  = red[0][j] + red[1][j] + red[2][j] + red[3][j];
            float totq = red[0][4 + j] + red[1][4 + j] + red[2][4 + j] + red[3][4 + j];
            float mu = tot * invB;
            float var = totq * invB - mu * mu;
            float s2 = g[j] * rsqrtf(var + EPSV);
            sc[j] = s2;
            sh[j] = bb[j] - mu * s2;
        }
    }

    const int row = blockIdx.x * 256 + t;
    float4 v = reinterpret_cast<float4*>(out)[row];
    v.x = fmaf(v.x, sc[0], sh[0]);
    v.y = fmaf(v.y, sc[1], sh[1]);
    v.z = fmaf(v.z, sc[2], sh[2]);
    v.w = fmaf(v.w, sc[3], sh[3]);
    reinterpret_cast<float4*>(out)[row] = v;
}

// ===========================================================================
// Fallback path (round-2 kernels) — used if ws_size is too small
// ===========================================================================
__global__ __launch_bounds__(256) void k_transpose_fb(const float* __restrict__ in,
                                                      float* __restrict__ out)
{
    int i = blockIdx.x * 256 + threadIdx.x;
    if (i < 787 * 64) {
        int k = i >> 6, o = i & 63;
        out[i] = in[o * 787 + k];
    }
}

#define SF1F(ic, r, c) sf1[(ic) * 324 + (r) * 20 + (c)]

__global__ __launch_bounds__(256) void k_fused_fb(
    const float* __restrict__ x,
    const float* __restrict__ w1, const float* __restrict__ b1,
    const float* __restrict__ w2, const float* __restrict__ b2,
    const float* __restrict__ s1w, const float* __restrict__ s1b,
    const float* __restrict__ s2w, const float* __restrict__ s2b,
    const float* __restrict__ fw, const float* __restrict__ fb,
    const float* __restrict__ wt, const float* __restrict__ fc1b,
    const float* __restrict__ fc2w, const float* __restrict__ fc2b,
    float* __restrict__ pre)
{
    const int b = blockIdx.x;
    const int t = threadIdx.x;

    __shared__ float sxA[30][20];
    __shared__ float sxB[30][20];
    __shared__ float sf1[8 * 324];
    __shared__ float scomb[788];
    __shared__ float sw1[72];
    __shared__ float sb1[8];
    __shared__ float sw2p[16 * 76];
    __shared__ float sb2[16];
    __shared__ float sh1p[4][64];
    __shared__ float sh1[64];
    __shared__ float sred[4];
    __shared__ float ssm[27];

    for (int i = t; i < 600; i += 256) { (&sxA[0][0])[i] = 0.f; (&sxB[0][0])[i] = 0.f; }
    for (int i = t; i < 8 * 324; i += 256) sf1[i] = 0.f;
    if (t < 72) sw1[t] = w1[t];
    if (t < 8) sb1[t] = b1[t];
    for (int i = t; i < 1152; i += 256) {
        int oc = i / 72, rem = i - oc * 72;
        sw2p[oc * 76 + rem] = w2[i];
    }
    if (t < 16) sb2[t] = b2[t];
    if (t < 8) ssm[t] = s1w[t];
    else if (t < 12) ssm[t] = s1b[t - 8];
    else if (t < 20) ssm[t] = s2w[t - 12];
    else if (t < 22) ssm[t] = s2b[t - 20];
    else if (t < 26) ssm[t] = fw[t - 22];
    else if (t == 26) ssm[t] = fb[0];
    __syncthreads();

    const float* xb = x + (size_t)b * 784;
    for (int i = t; i < 784; i += 256) {
        int r = i / 28, c = i - (i / 28) * 28;
        float v = xb[i];
        int pr = r + 1, pc = c + 1;
        if (pc <= 15) sxA[pr][pc] = v;
        if (pc >= 14) sxB[pr][pc - 14] = v;
    }
    __syncthreads();

    {
        const float fw00 = ssm[22], fw01 = ssm[23], fw10 = ssm[24], fw11 = ssm[25];
        const float fbv = ssm[26];
        float fsum = 0.f;
        for (int i = t; i < 729; i += 256) {
            int r = i / 27, c = i - (i / 27) * 27;
            float x00, x01, x10, x11;
            if (c <= 13) {
                x00 = sxA[r + 1][c + 1]; x01 = sxA[r + 1][c + 2];
                x10 = sxA[r + 2][c + 1]; x11 = sxA[r + 2][c + 2];
            } else {
                int cb = c - 14;
                x00 = sxB[r + 1][cb + 1]; x01 = sxB[r + 1][cb + 2];
                x10 = sxB[r + 2][cb + 1]; x11 = sxB[r + 2][cb + 2];
            }
            float v = fbv;
            v = fmaf(x00, fw00, v); v = fmaf(x01, fw01, v);
            v = fmaf(x10, fw10, v); v = fmaf(x11, fw11, v);
            fsum += 1.f / (1.f + expf(-v));
        }
        #pragma unroll
        for (int off = 32; off > 0; off >>= 1)
            fsum += __shfl_xor(fsum, off, 64);
        if ((t & 63) == 0) sred[t >> 6] = fsum;
    }

    {
        const int half = t >> 7;
        const int id = t & 127;
        if (id < 112) {
            const int p = id >> 3, oc = id & 7;
            const float* base = half ? &sxB[0][0] : &sxA[0][0];
            float X[4][16];
            #pragma unroll
            for (int u = 0; u < 4; ++u) {
                const float4* rp = reinterpret_cast<const float4*>(base + (2 * p + u) * 20);
                float4 a = rp[0], bb4 = rp[1], c4 = rp[2], d4 = rp[3];
                X[u][0] = a.x;  X[u][1] = a.y;  X[u][2] = a.z;  X[u][3] = a.w;
                X[u][4] = bb4.x; X[u][5] = bb4.y; X[u][6] = bb4.z; X[u][7] = bb4.w;
                X[u][8] = c4.x;  X[u][9] = c4.y;  X[u][10] = c4.z; X[u][11] = c4.w;
                X[u][12] = d4.x; X[u][13] = d4.y; X[u][14] = d4.z; X[u][15] = d4.w;
            }
            float W[9];
            #pragma unroll
            for (int k = 0; k < 9; ++k) W[k] = sw1[oc * 9 + k];
            const float bias = sb1[oc];
            const int j0 = half * 7;
            #pragma unroll
            for (int jj = 0; jj < 7; ++jj) {
                float m = 0.f;
                #pragma unroll
                for (int dr = 0; dr < 2; ++dr)
                    #pragma unroll
                    for (int dc = 0; dc < 2; ++dc) {
                        float acc = bias;
                        #pragma unroll
                        for (int u = 0; u < 3; ++u)
                            #pragma unroll
                            for (int v = 0; v < 3; ++v)
                                acc = fmaf(X[dr + u][2 * jj + dc + v], W[u * 3 + v], acc);
                        m = fmaxf(m, acc);
                    }
                SF1F(oc, p + 1, j0 + jj + 1) = m;
            }
        }
    }
    __syncthreads();

    if (t < 112) {
        const int p = t >> 4, oc = t & 15;
        const float bias = sb2[oc];
        float acc[7][4];
        #pragma unroll
        for (int jj = 0; jj < 7; ++jj)
            #pragma unroll
            for (int s = 0; s < 4; ++s) acc[jj][s] = bias;
        for (int ic = 0; ic < 8; ++ic) {
            float X[4][16];
            #pragma unroll
            for (int u = 0; u < 4; ++u) {
                const float4* rp = reinterpret_cast<const float4*>(&SF1F(ic, 2 * p + u, 0));
                float4 a = rp[0], bb4 = rp[1], c4 = rp[2], d4 = rp[3];
                X[u][0] = a.x;  X[u][1] = a.y;  X[u][2] = a.z;  X[u][3] = a.w;
                X[u][4] = bb4.x; X[u][5] = bb4.y; X[u][6] = bb4.z; X[u][7] = bb4.w;
                X[u][8] = c4.x;  X[u][9] = c4.y;  X[u][10] = c4.z; X[u][11] = c4.w;
                X[u][12] = d4.x; X[u][13] = d4.y; X[u][14] = d4.z; X[u][15] = d4.w;
            }
            float W[9];
            #pragma unroll
            for (int k = 0; k < 9; ++k) W[k] = sw2p[oc * 76 + ic * 9 + k];
            #pragma unroll
            for (int jj = 0; jj < 7; ++jj)
                #pragma unroll
                for (int dr = 0; dr < 2; ++dr)
                    #pragma unroll
                    for (int dc = 0; dc < 2; ++dc)
                        #pragma unroll
                        for (int u = 0; u < 3; ++u)
                            #pragma unroll
                            for (int v = 0; v < 3; ++v)
                                acc[jj][dr * 2 + dc] =
                                    fmaf(X[dr + u][2 * jj + dc + v], W[u * 3 + v], acc[jj][dr * 2 + dc]);
        }
        #pragma unroll
        for (int jj = 0; jj < 7; ++jj) {
            float m = fmaxf(fmaxf(acc[jj][0], acc[jj][1]), fmaxf(acc[jj][2], acc[jj][3]));
            scomb[oc * 49 + p * 7 + jj] = fmaxf(m, 0.f);
        }
    }
    __syncthreads();

    if (t == 0) {
        scomb[786] = (sred[0] + sred[1] + sred[2] + sred[3]) * (1.f / 729.f);
        float f0 = scomb[0], f1 = scomb[1];
        float h[4];
        #pragma unroll
        for (int k = 0; k < 4; ++k)
            h[k] = tanhf(fmaf(f0, ssm[k * 2], fmaf(f1, ssm[k * 2 + 1], ssm[8 + k])));
        float l0 = ssm[20], l1 = ssm[21];
        #pragma unroll
        for (int k = 0; k < 4; ++k) {
            l0 = fmaf(h[k], ssm[12 + k], l0);
            l1 = fmaf(h[k], ssm[16 + k], l1);
        }
        float mx = fmaxf(l0, l1);
        float e0 = expf(l0 - mx), e1 = expf(l1 - mx);
        float inv = 1.f / (e0 + e1);
        scomb[784] = e0 * inv;
        scomb[785] = e1 * inv;
    }
    __syncthreads();

    {
        const int o = t & 63, w = t >> 6;
        const int k0 = w * 197;
        const int k1 = (w == 3) ? 787 : k0 + 197;
        const float* wp = wt + (size_t)k0 * 64 + o;
        float acc = 0.f;
        #pragma unroll 4
        for (int k = k0; k < k1; ++k) {
            acc = fmaf(scomb[k], *wp, acc);
            wp += 64;
        }
        sh1p[w][o] = acc;
    }
    __syncthreads();
    if (t < 64)
        sh1[t] = fmaxf(sh1p[0][t] + sh1p[1][t] + sh1p[2][t] + sh1p[3][t] + fc1b[t], 0.f);
    __syncthreads();

    {
        const int oo = t >> 6, lane = t & 63;
        float v = sh1[lane] * fc2w[oo * 64 + lane];
        #pragma unroll
        for (int off = 32; off > 0; off >>= 1)
            v += __shfl_xor(v, off, 64);
        if (lane == 0) pre[(size_t)b * 4 + oo] = v + fc2b[oo];
    }
}

__global__ __launch_bounds__(256) void k_bnstat_fb(const float* __restrict__ pre,
                                                   float* __restrict__ part)
{
    const int t = threadIdx.x;
    const int row = blockIdx.x * 256 + t;
    float4 v = reinterpret_cast<const float4*>(pre)[row];
    float s0 = v.x, s1 = v.y, s2 = v.z, s3 = v.w;
    float q0 = v.x * v.x, q1 = v.y * v.y, q2 = v.z * v.z, q3 = v.w * v.w;
    #pragma unroll
    for (int off = 32; off > 0; off >>= 1) {
        s0 += __shfl_xor(s0, off, 64);
        s1 += __shfl_xor(s1, off, 64);
        s2 += __shfl_xor(s2, off, 64);
        s3 += __shfl_xor(s3, off, 64);
        q0 += __shfl_xor(q0, off, 64);
        q1 += __shfl_xor(q1, off, 64);
        q2 += __shfl_xor(q2, off, 64);
        q3 += __shfl_xor(q3, off, 64);
    }
    __shared__ float acc[4][8];
    if ((t & 63) == 0) {
        int w = t >> 6;
        acc[w][0] = s0; acc[w][1] = s1; acc[w][2] = s2; acc[w][3] = s3;
        acc[w][4] = q0; acc[w][5] = q1; acc[w][6] = q2; acc[w][7] = q3;
    }
    __syncthreads();
    if (t < 8)
        part[blockIdx.x * 8 + t] = acc[0][t] + acc[1][t] + acc[2][t] + acc[3][t];
}

__global__ void k_bnfinal_fb(const float* __restrict__ part,
                             const float* __restrict__ g, const float* __restrict__ bb,
                             float* __restrict__ ss, int nblocks)
{
    const int t = threadIdx.x;  // 64
    float s[8];
    #pragma unroll
    for (int i = 0; i < 8; ++i) s[i] = 0.f;
    for (int idx = t; idx < nblocks; idx += 64)
        #pragma unroll
        for (int i = 0; i < 8; ++i) s[i] += part[idx * 8 + i];
    #pragma unroll
    for (int i = 0; i < 8; ++i)
        #pragma unroll
        for (int off = 32; off > 0; off >>= 1)
            s[i] += __shfl_xor(s[i], off, 64);
    if (t == 0) {
        const float invB = 1.f / 16384.f;
        #pragma unroll
        for (int j = 0; j < 4; ++j) {
            float mu = s[j] * invB;
            float var = s[4 + j] * invB - mu * mu;
            float sc = g[j] * rsqrtf(var + EPSV);
            ss[j] = sc;
            ss[4 + j] = bb[j] - mu * sc;
        }
    }
}

__global__ __launch_bounds__(256) void k_bnapply_fb(const float* __restrict__ ss,
                                                    float* __restrict__ out)
{
    const int row = blockIdx.x * 256 + threadIdx.x;
    float4 v = reinterpret_cast<float4*>(out)[row];
    v.x = fmaf(v.x, ss[0], ss[4]);
    v.y = fmaf(v.y, ss[1], ss[5]);
    v.z = fmaf(v.z, ss[2], ss[6]);
    v.w = fmaf(v.w, ss[3], ss[7]);
    reinterpret_cast<float4*>(out)[row] = v;
}

// ===========================================================================
extern "C" void kernel_launch(void* const* d_in, const int* in_sizes, int n_in,
                              void* d_out, int out_size, void* d_ws, size_t ws_size,
                              hipStream_t stream)
{
    const float* x    = (const float*)d_in[0];
    const float* w1   = (const float*)d_in[1];
    const float* b1   = (const float*)d_in[2];
    const float* w2   = (const float*)d_in[3];
    const float* b2   = (const float*)d_in[4];
    const float* s1w  = (const float*)d_in[5];
    const float* s1b  = (const float*)d_in[6];
    const float* s2w  = (const float*)d_in[7];
    const float* s2b  = (const float*)d_in[8];
    const float* fw   = (const float*)d_in[9];
    const float* fb   = (const float*)d_in[10];
    const float* fc1w = (const float*)d_in[11];
    const float* fc1b = (const float*)d_in[12];
    const float* fc2w = (const float*)d_in[13];
    const float* fc2b = (const float*)d_in[14];
    const float* bng  = (const float*)d_in[15];
    const float* bnb  = (const float*)d_in[16];

    float* out = (float*)d_out;

    const size_t COMB_BYTES = (size_t)NBATCH * 800 * 2;      // 26,214,400
    const size_t WT_BYTES   = 64 * 800 * 2;                  // 102,400
    const size_t AF16_BYTES = 1536 * 2;                      // 3,072
    const size_t W1H2_BYTES = 72 * 4;                        // 288
    const size_t B1H2_BYTES = 8 * 4;                         // 32
    const size_t PART_BYTES = 256 * 8 * 4;                   // 8,192
    const size_t NEED = COMB_BYTES + WT_BYTES + AF16_BYTES + W1H2_BYTES +
                        B1H2_BYTES + PART_BYTES + 32;

    if (ws_size >= NEED) {
        char* p = (char*)d_ws;
        unsigned short* comb = (unsigned short*)p;                     p += COMB_BYTES;
        unsigned short* wtbf = (unsigned short*)p;                     p += WT_BYTES;
        unsigned short* af16 = (unsigned short*)p;                     p += AF16_BYTES;
        unsigned int*   w1h2 = (unsigned int*)p;                       p += W1H2_BYTES;
        unsigned int*   b1h2 = (unsigned int*)p;                       p += B1H2_BYTES;
        float*          part = (float*)p;

        k_prep<<<207, 256, 0, stream>>>(fc1w, w2, w1, b1, wtbf, af16, w1h2, b1h2);
        k_conv<<<NBATCH, 64, 0, stream>>>(x, s1w, s1b, s2w, s2b, fw, fb, b2,
                                          af16, w1h2, b1h2, comb);
        k_fc<<<256, 256, 0, stream>>>(comb, wtbf, fc1b, fc2w, fc2b, out, part);
        k_bnapply<<<64, 256, 0, stream>>>(part, bng, bnb, out);
    } else {
        float* part = (float*)d_ws;
        float* ss   = part + 512;
        float* wt   = ss + 8;

        k_transpose_fb<<<197, 256, 0, stream>>>(fc1w, wt);
        k_fused_fb<<<NBATCH, 256, 0, stream>>>(x, w1, b1, w2, b2, s1w, s1b, s2w, s2b,
                                               fw, fb, wt, fc1b, fc2w, fc2b, out);
        k_bnstat_fb<<<64, 256, 0, stream>>>(out, part);
        k_bnfinal_fb<<<1, 64, 0, stream>>>(part, bng, bnb, ss, 64);
        k_bnapply_fb<<<64, 256, 0, stream>>>(ss, out);
    }
}

// Round 15
// 87.091 us; speedup vs baseline: 1.0982x; 1.0002x over previous
//
#include <hip/hip_runtime.h>
#include <hip/hip_fp16.h>
#include <math.h>

#define NBATCH 16384
#define EPSV 1e-5f

typedef short short8 __attribute__((ext_vector_type(8)));
typedef _Float16 half8_t __attribute__((ext_vector_type(8)));
typedef short short2v __attribute__((ext_vector_type(2)));
typedef float f32x4 __attribute__((ext_vector_type(4)));
union V8 { uint4 u; short8 s; };
union VH { uint4 u; half8_t h; };

__device__ __forceinline__ unsigned short f2bf(float f) {
    unsigned int x = __float_as_uint(f);
    return (unsigned short)((x + 0x7fffu + ((x >> 16) & 1u)) >> 16);  // RNE
}
__device__ __forceinline__ unsigned short f2h(float f) {
    return __half_as_ushort(__float2half(f));   // v_cvt_f16_f32, RNE
}
__device__ __forceinline__ __half2 u2h(unsigned int u) { return __builtin_bit_cast(__half2, u); }
__device__ __forceinline__ unsigned int h2u(__half2 h) { return __builtin_bit_cast(unsigned int, h); }

// ---------------------------------------------------------------------------
// K0: prep all weight transforms once.
//   wt f16 [64][800] with PERMUTED K: k<784 -> k = pos*16 + oc  (oc<16, pos<49)
//   maps to fc1w[n][oc*49 + pos]; k in {784,785,786} identity; k>=787 zero.
// ---------------------------------------------------------------------------
__global__ __launch_bounds__(256) void k_prep(
    const float* __restrict__ fc1w, const float* __restrict__ w2,
    const float* __restrict__ w1, const float* __restrict__ b1,
    unsigned short* __restrict__ wt, unsigned short* __restrict__ af16,
    unsigned int* __restrict__ w1h2, unsigned int* __restrict__ b1h2)
{
    int i = blockIdx.x * 256 + threadIdx.x;
    if (i < 51200) {
        int n = i / 800, k = i - n * 800;
        float v;
        if (k < 784) {
            int pos = k >> 4, oc = k & 15;
            v = fc1w[n * 787 + oc * 49 + pos];
        } else if (k < 787) {
            v = fc1w[n * 787 + k];
        } else {
            v = 0.f;
        }
        wt[i] = f2h(v);
    } else if (i < 52736) {
        int a = i - 51200;
        int slot = a >> 7, rem = a & 127, oc = rem >> 3, ic = rem & 7;
        float v = (slot < 9) ? w2[oc * 72 + ic * 9 + slot] : 0.f;
        af16[a] = f2h(v);
    } else if (i < 52808) {
        int k = i - 52736;
        unsigned int hb = f2h(w1[k]);
        w1h2[k] = hb | (hb << 16);
    } else if (i < 52816) {
        int k = i - 52808;
        unsigned int hb = f2h(b1[k]);
        b1h2[k] = hb | (hb << 16);
    }
}

// ---------------------------------------------------------------------------
// K1: one wave = one block = one image (round-11 structure, best measured);
//     rolled phase loops; r12 permuted-K b64 epilogue stores; no barriers.
// ---------------------------------------------------------------------------
#define SXS 15   // sxu row stride in u32

__global__ __launch_bounds__(64, 8) void k_conv(
    const float* __restrict__ x,
    const float* __restrict__ s1w, const float* __restrict__ s1b,
    const float* __restrict__ s2w, const float* __restrict__ s2b,
    const float* __restrict__ fw, const float* __restrict__ fb,
    const float* __restrict__ b2,
    const unsigned short* __restrict__ Afg,   // [12][16][8] f16
    const unsigned int* __restrict__ w1h2g,   // [72]
    const unsigned int* __restrict__ b1h2g,   // [8]
    unsigned short* __restrict__ comb)
{
    const int l = threadIdx.x;

    __shared__ unsigned int sxu[30 * SXS];                 // f16 col-pairs
    __shared__ __align__(16) unsigned short sf1[16 * 136]; // conv1 pooled, channels-last f16

    // ---- init (wave-private; no barriers anywhere) --------------------------
    for (int i = l; i < 30 * SXS; i += 64) sxu[i] = 0u;
    if (l < 60) {   // sf1 pad ring
        int R, C;
        if (l < 16)      { R = 0;      C = l; }
        else if (l < 32) { R = 15;     C = l - 16; }
        else if (l < 46) { R = l - 31; C = 0; }
        else             { R = l - 45; C = 15; }
        *reinterpret_cast<uint4*>(&sf1[R * 136 + C * 8]) = uint4{0u, 0u, 0u, 0u};
    }

    // filter weights: uniform addresses -> scalar loads
    const __half2 fwh0 = __float2half2_rn(fw[0]);
    const __half2 fwh1 = __float2half2_rn(fw[1]);
    const __half2 fwh2 = __float2half2_rn(fw[2]);
    const __half2 fwh3 = __float2half2_rn(fw[3]);
    const __half2 fbh  = __float2half2_rn(fb[0]);

    // conv2 MFMA lane constants
    const int n = l & 15, g = l >> 4;
    const int qr = n & 7;
    const int q = (qr < 7) ? qr : 6;       // clamp dead lane
    const int dr = n >> 3;
    VH af[3];
    const unsigned short* ps[3];
    #pragma unroll
    for (int s = 0; s < 3; ++s) {
        const int slot = s * 4 + g;
        const int u = slot / 3, v = slot - 3 * (slot / 3);
        const int offs = (slot <= 8) ? (u * 136 + v * 8) : 0;
        ps[s] = sf1 + dr * 136 + 16 * q + offs;   // pp adds 272 u16
        af[s].u = *reinterpret_cast<const uint4*>(Afg + ((slot * 16 + n) << 3));
    }
    float biasv[4];
    #pragma unroll
    for (int i = 0; i < 4; ++i) biasv[i] = b2[4 * g + i];

    // stage-phase lane constants
    int srow[7], sww[7];
    #pragma unroll
    for (int k = 0; k < 7; ++k) {
        int u0 = l + k * 64;
        srow[k] = u0 / 15;
        sww[k]  = u0 - srow[k] * 15;
    }

    // ---- this block's image ------------------------------------------------
    const int b = blockIdx.x;
    const float* xb = x + (size_t)b * 784;
    unsigned short* crow = comb + (size_t)b * 800;

    // zero the K-tail early (wt is 0 there, but comb holds poisoned bytes)
    if (l < 13) crow[787 + l] = 0;

    // stage x: batch ALL global loads first (misses overlap), then cvt+write
    float xlo[7], xhi[7];
    #pragma unroll
    for (int k = 0; k < 7; ++k) {
        const int u0 = l + k * 64;
        if (u0 < 420) {
            const float* base = xb + srow[k] * 28;
            xlo[k] = (sww[k] == 0)  ? 0.f : base[2 * sww[k] - 1];
            xhi[k] = (sww[k] == 14) ? 0.f : base[2 * sww[k]];
        }
    }
    #pragma unroll
    for (int k = 0; k < 7; ++k) {
        const int u0 = l + k * 64;
        if (u0 < 420)
            sxu[(srow[k] + 1) * SXS + sww[k]] = h2u(__floats2half2_rn(xlo[k], xhi[k]));
    }

    // ---- filter conv (2 positions per unit, packed f16) + sigmoid wave-sum --
    float fsum = 0.f;
    for (int u0 = l; u0 < 378; u0 += 64) {
        int r = u0 / 14, cp = u0 - (u0 / 14) * 14;
        unsigned int A1 = sxu[(r + 1) * SXS + cp], B1 = sxu[(r + 1) * SXS + cp + 1];
        unsigned int A2 = sxu[(r + 2) * SXS + cp], B2 = sxu[(r + 2) * SXS + cp + 1];
        __half2 al1 = u2h(__builtin_amdgcn_alignbit(B1, A1, 16));
        __half2 al2 = u2h(__builtin_amdgcn_alignbit(B2, A2, 16));
        __half2 acc = __hfma2(fwh0, al1,
                      __hfma2(fwh1, u2h(B1),
                      __hfma2(fwh2, al2,
                      __hfma2(fwh3, u2h(B2), fbh))));
        float2 f = __half22float2(acc);
        fsum += __frcp_rn(1.f + __expf(-f.x));
        if (cp < 13) fsum += __frcp_rn(1.f + __expf(-f.y));
    }
    #pragma unroll
    for (int off = 32; off > 0; off >>= 1)
        fsum += __shfl_xor(fsum, off, 64);

    // ---- conv1: pooled cell (p,j), 8 oc, packed f16 --------------------------
    for (int i = l; i < 196; i += 64) {
        const int p = i / 14, j = i - (i / 14) * 14;
        unsigned int A[4], B[4], M[4];
        #pragma unroll
        for (int u = 0; u < 4; ++u) {
            A[u] = sxu[(2 * p + u) * SXS + j];
            B[u] = sxu[(2 * p + u) * SXS + j + 1];
            M[u] = __builtin_amdgcn_alignbit(B[u], A[u], 16);
        }
        unsigned short outv[8];
        #pragma unroll
        for (int oc = 0; oc < 8; ++oc) {
            __half2 a0 = u2h(b1h2g[oc]), a1 = a0;
            #pragma unroll
            for (int u = 0; u < 3; ++u) {
                #pragma unroll
                for (int v = 0; v < 3; ++v) {
                    const __half2 wv = u2h(w1h2g[oc * 9 + u * 3 + v]);
                    const unsigned int p0 = (v == 0) ? A[u]     : ((v == 1) ? M[u]     : B[u]);
                    const unsigned int p1 = (v == 0) ? A[u + 1] : ((v == 1) ? M[u + 1] : B[u + 1]);
                    a0 = __hfma2(wv, u2h(p0), a0);
                    a1 = __hfma2(wv, u2h(p1), a1);
                }
            }
            short2v s0 = __builtin_bit_cast(short2v, a0);
            short2v s1 = __builtin_bit_cast(short2v, a1);
            short2v mm = __builtin_elementwise_max(s0, s1);
            short m = mm[0] > mm[1] ? mm[0] : mm[1];
            if (m < 0) m = 0;
            outv[oc] = (unsigned short)m;
        }
        *reinterpret_cast<uint4*>(&sf1[(p + 1) * 136 + (j + 1) * 8]) =
            *reinterpret_cast<const uint4*>(outv);
    }

    // ---- conv2 via f16 MFMA; permuted-K b64 stores ---------------------------
    float f0r = 0.f, f1r = 0.f;
    for (int pp = 0; pp < 7; ++pp) {
        f32x4 acc0 = {0.f, 0.f, 0.f, 0.f}, acc1 = {0.f, 0.f, 0.f, 0.f};
        #pragma unroll
        for (int s = 0; s < 3; ++s) {
            VH c0, c1;
            c0.u = *reinterpret_cast<const uint4*>(ps[s] + pp * 272);
            c1.u = *reinterpret_cast<const uint4*>(ps[s] + pp * 272 + 8);
            acc0 = __builtin_amdgcn_mfma_f32_16x16x32_f16(af[s].h, c0.h, acc0, 0, 0, 0);
            acc1 = __builtin_amdgcn_mfma_f32_16x16x32_f16(af[s].h, c1.h, acc1, 0, 0, 0);
        }
        float vv[4];
        #pragma unroll
        for (int i = 0; i < 4; ++i) {
            float m = fmaxf(acc0[i], acc1[i]);            // max over dc
            m = fmaxf(m, __shfl_xor(m, 8, 64));           // max over dr
            vv[i] = fmaxf(m + biasv[i], 0.f);
        }
        if (pp == 0) {
            f0r = __shfl(vv[0], 0, 64);                   // flat[0] (oc0,pos0)
            f1r = __shfl(vv[0], 1, 64);                   // flat[1] (oc0,pos1)
        }
        if (n < 7) {
            uint2 pk;
            pk.x = (unsigned int)f2h(vv[0]) | ((unsigned int)f2h(vv[1]) << 16);
            pk.y = (unsigned int)f2h(vv[2]) | ((unsigned int)f2h(vv[3]) << 16);
            *reinterpret_cast<uint2*>(&crow[(pp * 7 + q) * 16 + g * 4]) = pk;
        }
    }

    // ---- sampler + filter-mean (lane 0) --------------------------------------
    if (l == 0) {
        crow[786] = f2h(fsum * (1.f / 729.f));
        float h[4];
        #pragma unroll
        for (int k = 0; k < 4; ++k) {
            float y = fmaf(f0r, s1w[2 * k], fmaf(f1r, s1w[2 * k + 1], s1b[k]));
            float e = __expf(2.f * y);
            h[k] = (e - 1.f) * __frcp_rn(e + 1.f);
        }
        float l0 = s2b[0], l1 = s2b[1];
        #pragma unroll
        for (int k = 0; k < 4; ++k) {
            l0 = fmaf(h[k], s2w[k], l0);
            l1 = fmaf(h[k], s2w[4 + k], l1);
        }
        float mx = fmaxf(l0, l1);
        float e0 = __expf(l0 - mx), e1 = __expf(l1 - mx);
        float inv = __frcp_rn(e0 + e1);
        crow[784] = f2h(e0 * inv);
        crow[785] = f2h(e1 * inv);
    }
}

// ---------------------------------------------------------------------------
// K2: f16 MFMA GEMM  h1 = relu(comb[16384,800] @ wt[64,800]^T + fc1b)
//     epilogue: out = h1 @ fc2w^T + fc2b  (+ per-block BN partial stats)
// ---------------------------------------------------------------------------
__global__ __launch_bounds__(256) void k_fc(
    const unsigned short* __restrict__ A,
    const unsigned short* __restrict__ Bw,
    const float* __restrict__ fc1b,
    const float* __restrict__ fc2w, const float* __restrict__ fc2b,
    float* __restrict__ out, float* __restrict__ part)
{
    __shared__ uint4 Asm[2][256];
    __shared__ uint4 Bsm[2][256];
    __shared__ float sh[64][68];
    __shared__ float sfc2[4][64];
    __shared__ float pacc[4][8];

    const int t = threadIdx.x;
    const int w = t >> 6, l = t & 63;
    const int blk = blockIdx.x;

    sfc2[t >> 6][t & 63] = fc2w[t];

    const int srow = t >> 2, skbp = t & 3;
    const int skbl = skbp ^ ((srow >> 1) & 3);
    const uint4* Ag = reinterpret_cast<const uint4*>(A) + ((size_t)blk * 64 + srow) * 100;
    const uint4* Bg = reinterpret_cast<const uint4*>(Bw) + (size_t)srow * 100;
    const int sidx = srow * 4 + skbp;

    const int arow = w * 16 + (l & 15);
    const int aidx = arow * 4 + ((l >> 4) ^ ((arow >> 1) & 3));
    int bidx[4];
    #pragma unroll
    for (int nf = 0; nf < 4; ++nf) {
        int nn = nf * 16 + (l & 15);
        bidx[nf] = nn * 4 + ((l >> 4) ^ ((nn >> 1) & 3));
    }

    f32x4 acc0 = {0.f, 0.f, 0.f, 0.f}, acc1 = acc0, acc2 = acc0, acc3 = acc0;

    Asm[0][sidx] = Ag[skbl];
    Bsm[0][sidx] = Bg[skbl];

    int buf = 0;
    for (int s = 0; s < 25; ++s) {
        __syncthreads();
        if (s < 24) {
            Asm[buf ^ 1][sidx] = Ag[(s + 1) * 4 + skbl];
            Bsm[buf ^ 1][sidx] = Bg[(s + 1) * 4 + skbl];
        }
        VH av; av.u = Asm[buf][aidx];
        VH b0; b0.u = Bsm[buf][bidx[0]];
        VH b1; b1.u = Bsm[buf][bidx[1]];
        VH b2; b2.u = Bsm[buf][bidx[2]];
        VH b3; b3.u = Bsm[buf][bidx[3]];
        acc0 = __builtin_amdgcn_mfma_f32_16x16x32_f16(av.h, b0.h, acc0, 0, 0, 0);
        acc1 = __builtin_amdgcn_mfma_f32_16x16x32_f16(av.h, b1.h, acc1, 0, 0, 0);
        acc2 = __builtin_amdgcn_mfma_f32_16x16x32_f16(av.h, b2.h, acc2, 0, 0, 0);
        acc3 = __builtin_amdgcn_mfma_f32_16x16x32_f16(av.h, b3.h, acc3, 0, 0, 0);
        buf ^= 1;
    }

    {
        const int c0 = l & 15, r0 = w * 16 + (l >> 4) * 4;
        float fb0 = fc1b[c0], fb1 = fc1b[16 + c0], fb2 = fc1b[32 + c0], fb3 = fc1b[48 + c0];
        #pragma unroll
        for (int r = 0; r < 4; ++r) {
            sh[r0 + r][c0]      = fmaxf(acc0[r] + fb0, 0.f);
            sh[r0 + r][16 + c0] = fmaxf(acc1[r] + fb1, 0.f);
            sh[r0 + r][32 + c0] = fmaxf(acc2[r] + fb2, 0.f);
            sh[r0 + r][48 + c0] = fmaxf(acc3[r] + fb3, 0.f);
        }
    }
    __syncthreads();

    {
        const int row = t >> 2, oo = t & 3;
        float s = fc2b[oo];
        #pragma unroll 8
        for (int o = 0; o < 64; ++o)
            s = fmaf(sh[row][o], sfc2[oo][o], s);
        out[((size_t)blk * 64 + row) * 4 + oo] = s;

        float rs = s, rq = s * s;
        #pragma unroll
        for (int off = 4; off < 64; off <<= 1) {
            rs += __shfl_xor(rs, off, 64);
            rq += __shfl_xor(rq, off, 64);
        }
        if (l < 4) pacc[w][l] = rs;
        else if (l < 8) pacc[w][l] = rq;
    }
    __syncthreads();
    if (t < 8)
        part[blk * 8 + t] = pacc[0][t] + pacc[1][t] + pacc[2][t] + pacc[3][t];
}

// ---------------------------------------------------------------------------
// K3: merged BN finalize + apply. 64 blocks x 256 threads; each block reduces
//     part[256][8] itself (2048 floats, deterministic) and normalizes its
//     256-row chunk of out in place. Deletes the separate k_bnfinal launch.
// ---------------------------------------------------------------------------
__global__ __launch_bounds__(256) void k_bnapply(const float* __restrict__ part,
                                                 const float* __restrict__ g,
                                                 const float* __restrict__ bb,
                                                 float* __restrict__ out)
{
    const int t = threadIdx.x;
    __shared__ float red[4][8];

    float s[8];
    #pragma unroll
    for (int i = 0; i < 8; ++i) s[i] = part[t * 8 + i];
    #pragma unroll
    for (int i = 0; i < 8; ++i)
        #pragma unroll
        for (int off = 32; off > 0; off >>= 1)
            s[i] += __shfl_xor(s[i], off, 64);
    if ((t & 63) == 0) {
        #pragma unroll
        for (int i = 0; i < 8; ++i) red[t >> 6][i] = s[i];
    }
    __syncthreads();

    float sc[4], sh[4];
    {
        const float invB = 1.f / 16384.f;
        #pragma unroll
        for (int j = 0; j < 4; ++j) {
            float tot  = red[0][j] + red[1][j] + red[2][j] + red[3][j];
            float totq = red[0][4 + j] + red[1][4 + j] + red[2][4 + j] + red[3][4 + j];
            float mu = tot * invB;
            float var = totq * invB - mu * mu;
            float s2 = g[j] * rsqrtf(var + EPSV);
            sc[j] = s2;
            sh[j] = bb[j] - mu * s2;
        }
    }

    const int row = blockIdx.x * 256 + t;
    float4 v = reinterpret_cast<float4*>(out)[row];
    v.x = fmaf(v.x, sc[0], sh[0]);
    v.y = fmaf(v.y, sc[1], sh[1]);
    v.z = fmaf(v.z, sc[2], sh[2]);
    v.w = fmaf(v.w, sc[3], sh[3]);
    reinterpret_cast<float4*>(out)[row] = v;
}

// ===========================================================================
// Fallback path (round-2 kernels) — used if ws_size is too small
// ===========================================================================
__global__ __launch_bounds__(256) void k_transpose_fb(const float* __restrict__ in,
                                                      float* __restrict__ out)
{
    int i = blockIdx.x * 256 + threadIdx.x;
    if (i < 787 * 64) {
        int k = i >> 6, o = i & 63;
        out[i] = in[o * 787 + k];
    }
}

#define SF1F(ic, r, c) sf1[(ic) * 324 + (r) * 20 + (c)]

__global__ __launch_bounds__(256) void k_fused_fb(
    const float* __restrict__ x,
    const float* __restrict__ w1, const float* __restrict__ b1,
    const float* __restrict__ w2, const float* __restrict__ b2,
    const float* __restrict__ s1w, const float* __restrict__ s1b,
    const float* __restrict__ s2w, const float* __restrict__ s2b,
    const float* __restrict__ fw, const float* __restrict__ fb,
    const float* __restrict__ wt, const float* __restrict__ fc1b,
    const float* __restrict__ fc2w, const float* __restrict__ fc2b,
    float* __restrict__ pre)
{
    const int b = blockIdx.x;
    const int t = threadIdx.x;

    __shared__ float sxA[30][20];
    __shared__ float sxB[30][20];
    __shared__ float sf1[8 * 324];
    __shared__ float scomb[788];
    __shared__ float sw1[72];
    __shared__ float sb1[8];
    __shared__ float sw2p[16 * 76];
    __shared__ float sb2[16];
    __shared__ float sh1p[4][64];
    __shared__ float sh1[64];
    __shared__ float sred[4];
    __shared__ float ssm[27];

    for (int i = t; i < 600; i += 256) { (&sxA[0][0])[i] = 0.f; (&sxB[0][0])[i] = 0.f; }
    for (int i = t; i < 8 * 324; i += 256) sf1[i] = 0.f;
    if (t < 72) sw1[t] = w1[t];
    if (t < 8) sb1[t] = b1[t];
    for (int i = t; i < 1152; i += 256) {
        int oc = i / 72, rem = i - oc * 72;
        sw2p[oc * 76 + rem] = w2[i];
    }
    if (t < 16) sb2[t] = b2[t];
    if (t < 8) ssm[t] = s1w[t];
    else if (t < 12) ssm[t] = s1b[t - 8];
    else if (t < 20) ssm[t] = s2w[t - 12];
    else if (t < 22) ssm[t] = s2b[t - 20];
    else if (t < 26) ssm[t] = fw[t - 22];
    else if (t == 26) ssm[t] = fb[0];
    __syncthreads();

    const float* xb = x + (size_t)b * 784;
    for (int i = t; i < 784; i += 256) {
        int r = i / 28, c = i - (i / 28) * 28;
        float v = xb[i];
        int pr = r + 1, pc = c + 1;
        if (pc <= 15) sxA[pr][pc] = v;
        if (pc >= 14) sxB[pr][pc - 14] = v;
    }
    __syncthreads();

    {
        const float fw00 = ssm[22], fw01 = ssm[23], fw10 = ssm[24], fw11 = ssm[25];
        const float fbv = ssm[26];
        float fsum = 0.f;
        for (int i = t; i < 729; i += 256) {
            int r = i / 27, c = i - (i / 27) * 27;
            float x00, x01, x10, x11;
            if (c <= 13) {
                x00 = sxA[r + 1][c + 1]; x01 = sxA[r + 1][c + 2];
                x10 = sxA[r + 2][c + 1]; x11 = sxA[r + 2][c + 2];
            } else {
                int cb = c - 14;
                x00 = sxB[r + 1][cb + 1]; x01 = sxB[r + 1][cb + 2];
                x10 = sxB[r + 2][cb + 1]; x11 = sxB[r + 2][cb + 2];
            }
            float v = fbv;
            v = fmaf(x00, fw00, v); v = fmaf(x01, fw01, v);
            v = fmaf(x10, fw10, v); v = fmaf(x11, fw11, v);
            fsum += 1.f / (1.f + expf(-v));
        }
        #pragma unroll
        for (int off = 32; off > 0; off >>= 1)
            fsum += __shfl_xor(fsum, off, 64);
        if ((t & 63) == 0) sred[t >> 6] = fsum;
    }

    {
        const int half = t >> 7;
        const int id = t & 127;
        if (id < 112) {
            const int p = id >> 3, oc = id & 7;
            const float* base = half ? &sxB[0][0] : &sxA[0][0];
            float X[4][16];
            #pragma unroll
            for (int u = 0; u < 4; ++u) {
                const float4* rp = reinterpret_cast<const float4*>(base + (2 * p + u) * 20);
                float4 a = rp[0], bb4 = rp[1], c4 = rp[2], d4 = rp[3];
                X[u][0] = a.x;  X[u][1] = a.y;  X[u][2] = a.z;  X[u][3] = a.w;
                X[u][4] = bb4.x; X[u][5] = bb4.y; X[u][6] = bb4.z; X[u][7] = bb4.w;
                X[u][8] = c4.x;  X[u][9] = c4.y;  X[u][10] = c4.z; X[u][11] = c4.w;
                X[u][12] = d4.x; X[u][13] = d4.y; X[u][14] = d4.z; X[u][15] = d4.w;
            }
            float W[9];
            #pragma unroll
            for (int k = 0; k < 9; ++k) W[k] = sw1[oc * 9 + k];
            const float bias = sb1[oc];
            const int j0 = half * 7;
            #pragma unroll
            for (int jj = 0; jj < 7; ++jj) {
                float m = 0.f;
                #pragma unroll
                for (int dr = 0; dr < 2; ++dr)
                    #pragma unroll
                    for (int dc = 0; dc < 2; ++dc) {
                        float acc = bias;
                        #pragma unroll
                        for (int u = 0; u < 3; ++u)
                            #pragma unroll
                            for (int v = 0; v < 3; ++v)
                                acc = fmaf(X[dr + u][2 * jj + dc + v], W[u * 3 + v], acc);
                        m = fmaxf(m, acc);
                    }
                SF1F(oc, p + 1, j0 + jj + 1) = m;
            }
        }
    }
    __syncthreads();

    if (t < 112) {
        const int p = t >> 4, oc = t & 15;
        const float bias = sb2[oc];
        float acc[7][4];
        #pragma unroll
        for (int jj = 0; jj < 7; ++jj)
            #pragma unroll
            for (int s = 0; s < 4; ++s) acc[jj][s] = bias;
        for (int ic = 0; ic < 8; ++ic) {
            float X[4][16];
            #pragma unroll
            for (int u = 0; u < 4; ++u) {
                const float4* rp = reinterpret_cast<const float4*>(&SF1F(ic, 2 * p + u, 0));
                float4 a = rp[0], bb4 = rp[1], c4 = rp[2], d4 = rp[3];
                X[u][0] = a.x;  X[u][1] = a.y;  X[u][2] = a.z;  X[u][3] = a.w;
                X[u][4] = bb4.x; X[u][5] = bb4.y; X[u][6] = bb4.z; X[u][7] = bb4.w;
                X[u][8] = c4.x;  X[u][9] = c4.y;  X[u][10] = c4.z; X[u][11] = c4.w;
                X[u][12] = d4.x; X[u][13] = d4.y; X[u][14] = d4.z; X[u][15] = d4.w;
            }
            float W[9];
            #pragma unroll
            for (int k = 0; k < 9; ++k) W[k] = sw2p[oc * 76 + ic * 9 + k];
            #pragma unroll
            for (int jj = 0; jj < 7; ++jj)
                #pragma unroll
                for (int dr = 0; dr < 2; ++dr)
                    #pragma unroll
                    for (int dc = 0; dc < 2; ++dc)
                        #pragma unroll
                        for (int u = 0; u < 3; ++u)
                            #pragma unroll
                            for (int v = 0; v < 3; ++v)
                                acc[jj][dr * 2 + dc] =
                                    fmaf(X[dr + u][2 * jj + dc + v], W[u * 3 + v], acc[jj][dr * 2 + dc]);
        }
        #pragma unroll
        for (int jj = 0; jj < 7; ++jj) {
            float m = fmaxf(fmaxf(acc[jj][0], acc[jj][1]), fmaxf(acc[jj][2], acc[jj][3]));
            scomb[oc * 49 + p * 7 + jj] = fmaxf(m, 0.f);
        }
    }
    __syncthreads();

    if (t == 0) {
        scomb[786] = (sred[0] + sred[1] + sred[2] + sred[3]) * (1.f / 729.f);
        float f0 = scomb[0], f1 = scomb[1];
        float h[4];
        #pragma unroll
        for (int k = 0; k < 4; ++k)
            h[k] = tanhf(fmaf(f0, ssm[k * 2], fmaf(f1, ssm[k * 2 + 1], ssm[8 + k])));
        float l0 = ssm[20], l1 = ssm[21];
        #pragma unroll
        for (int k = 0; k < 4; ++k) {
            l0 = fmaf(h[k], ssm[12 + k], l0);
            l1 = fmaf(h[k], ssm[16 + k], l1);
        }
        float mx = fmaxf(l0, l1);
        float e0 = expf(l0 - mx), e1 = expf(l1 - mx);
        float inv = 1.f / (e0 + e1);
        scomb[784] = e0 * inv;
        scomb[785] = e1 * inv;
    }
    __syncthreads();

    {
        const int o = t & 63, w = t >> 6;
        const int k0 = w * 197;
        const int k1 = (w == 3) ? 787 : k0 + 197;
        const float* wp = wt + (size_t)k0 * 64 + o;
        float acc = 0.f;
        #pragma unroll 4
        for (int k = k0; k < k1; ++k) {
            acc = fmaf(scomb[k], *wp, acc);
            wp += 64;
        }
        sh1p[w][o] = acc;
    }
    __syncthreads();
    if (t < 64)
        sh1[t] = fmaxf(sh1p[0][t] + sh1p[1][t] + sh1p[2][t] + sh1p[3][t] + fc1b[t], 0.f);
    __syncthreads();

    {
        const int oo = t >> 6, lane = t & 63;
        float v = sh1[lane] * fc2w[oo * 64 + lane];
        #pragma unroll
        for (int off = 32; off > 0; off >>= 1)
            v += __shfl_xor(v, off, 64);
        if (lane == 0) pre[(size_t)b * 4 + oo] = v + fc2b[oo];
    }
}

__global__ __launch_bounds__(256) void k_bnstat_fb(const float* __restrict__ pre,
                                                   float* __restrict__ part)
{
    const int t = threadIdx.x;
    const int row = blockIdx.x * 256 + t;
    float4 v = reinterpret_cast<const float4*>(pre)[row];
    float s0 = v.x, s1 = v.y, s2 = v.z, s3 = v.w;
    float q0 = v.x * v.x, q1 = v.y * v.y, q2 = v.z * v.z, q3 = v.w * v.w;
    #pragma unroll
    for (int off = 32; off > 0; off >>= 1) {
        s0 += __shfl_xor(s0, off, 64);
        s1 += __shfl_xor(s1, off, 64);
        s2 += __shfl_xor(s2, off, 64);
        s3 += __shfl_xor(s3, off, 64);
        q0 += __shfl_xor(q0, off, 64);
        q1 += __shfl_xor(q1, off, 64);
        q2 += __shfl_xor(q2, off, 64);
        q3 += __shfl_xor(q3, off, 64);
    }
    __shared__ float acc[4][8];
    if ((t & 63) == 0) {
        int w = t >> 6;
        acc[w][0] = s0; acc[w][1] = s1; acc[w][2] = s2; acc[w][3] = s3;
        acc[w][4] = q0; acc[w][5] = q1; acc[w][6] = q2; acc[w][7] = q3;
    }
    __syncthreads();
    if (t < 8)
        part[blockIdx.x * 8 + t] = acc[0][t] + acc[1][t] + acc[2][t] + acc[3][t];
}

__global__ void k_bnfinal_fb(const float* __restrict__ part,
                             const float* __restrict__ g, const float* __restrict__ bb,
                             float* __restrict__ ss, int nblocks)
{
    const int t = threadIdx.x;  // 64
    float s[8];
    #pragma unroll
    for (int i = 0; i < 8; ++i) s[i] = 0.f;
    for (int idx = t; idx < nblocks; idx += 64)
        #pragma unroll
        for (int i = 0; i < 8; ++i) s[i] += part[idx * 8 + i];
    #pragma unroll
    for (int i = 0; i < 8; ++i)
        #pragma unroll
        for (int off = 32; off > 0; off >>= 1)
            s[i] += __shfl_xor(s[i], off, 64);
    if (t == 0) {
        const float invB = 1.f / 16384.f;
        #pragma unroll
        for (int j = 0; j < 4; ++j) {
            float mu = s[j] * invB;
            float var = s[4 + j] * invB - mu * mu;
            float sc = g[j] * rsqrtf(var + EPSV);
            ss[j] = sc;
            ss[4 + j] = bb[j] - mu * sc;
        }
    }
}

__global__ __launch_bounds__(256) void k_bnapply_fb(const float* __restrict__ ss,
                                                    float* __restrict__ out)
{
    const int row = blockIdx.x * 256 + threadIdx.x;
    float4 v = reinterpret_cast<float4*>(out)[row];
    v.x = fmaf(v.x, ss[0], ss[4]);
    v.y = fmaf(v.y, ss[1], ss[5]);
    v.z = fmaf(v.z, ss[2], ss[6]);
    v.w = fmaf(v.w, ss[3], ss[7]);
    reinterpret_cast<float4*>(out)[row] = v;
}

// ===========================================================================
extern "C" void kernel_launch(void* const* d_in, const int* in_sizes, int n_in,
                              void* d_out, int out_size, void* d_ws, size_t ws_size,
                              hipStream_t stream)
{
    const float* x    = (const float*)d_in[0];
    const float* w1   = (const float*)d_in[1];
    const float* b1   = (const float*)d_in[2];
    const float* w2   = (const float*)d_in[3];
    const float* b2   = (const float*)d_in[4];
    const float* s1w  = (const float*)d_in[5];
    const float* s1b  = (const float*)d_in[6];
    const float* s2w  = (const float*)d_in[7];
    const float* s2b  = (const float*)d_in[8];
    const float* fw   = (const float*)d_in[9];
    const float* fb   = (const float*)d_in[10];
    const float* fc1w = (const float*)d_in[11];
    const float* fc1b = (const float*)d_in[12];
    const float* fc2w = (const float*)d_in[13];
    const float* fc2b = (const float*)d_in[14];
    const float* bng  = (const float*)d_in[15];
    const float* bnb  = (const float*)d_in[16];

    float* out = (float*)d_out;

    const size_t COMB_BYTES = (size_t)NBATCH * 800 * 2;      // 26,214,400
    const size_t WT_BYTES   = 64 * 800 * 2;                  // 102,400
    const size_t AF16_BYTES = 1536 * 2;                      // 3,072
    const size_t W1H2_BYTES = 72 * 4;                        // 288
    const size_t B1H2_BYTES = 8 * 4;                         // 32
    const size_t PART_BYTES = 256 * 8 * 4;                   // 8,192
    const size_t NEED = COMB_BYTES + WT_BYTES + AF16_BYTES + W1H2_BYTES +
                        B1H2_BYTES + PART_BYTES + 32;

    if (ws_size >= NEED) {
        char* p = (char*)d_ws;
        unsigned short* comb = (unsigned short*)p;                     p += COMB_BYTES;
        unsigned short* wtbf = (unsigned short*)p;                     p += WT_BYTES;
        unsigned short* af16 = (unsigned short*)p;                     p += AF16_BYTES;
        unsigned int*   w1h2 = (unsigned int*)p;                       p += W1H2_BYTES;
        unsigned int*   b1h2 = (unsigned int*)p;                       p += B1H2_BYTES;
        float*          part = (float*)p;

        k_prep<<<207, 256, 0, stream>>>(fc1w, w2, w1, b1, wtbf, af16, w1h2, b1h2);
        k_conv<<<NBATCH, 64, 0, stream>>>(x, s1w, s1b, s2w, s2b, fw, fb, b2,
                                          af16, w1h2, b1h2, comb);
        k_fc<<<256, 256, 0, stream>>>(comb, wtbf, fc1b, fc2w, fc2b, out, part);
        k_bnapply<<<64, 256, 0, stream>>>(part, bng, bnb, out);
    } else {
        float* part = (float*)d_ws;
        float* ss   = part + 512;
        float* wt   = ss + 8;

        k_transpose_fb<<<197, 256, 0, stream>>>(fc1w, wt);
        k_fused_fb<<<NBATCH, 256, 0, stream>>>(x, w1, b1, w2, b2, s1w, s1b, s2w, s2b,
                                               fw, fb, wt, fc1b, fc2w, fc2b, out);
        k_bnstat_fb<<<64, 256, 0, stream>>>(out, part);
        k_bnfinal_fb<<<1, 64, 0, stream>>>(part, bng, bnb, ss, 64);
        k_bnapply_fb<<<64, 256, 0, stream>>>(ss, out);
    }
}